// Round 1
// 481.222 us; speedup vs baseline: 1.0798x; 1.0798x over previous
//
#include <hip/hip_runtime.h>
#include <cmath>

namespace {
constexpr int B = 8;
constexpr int T = 2048;
constexpr int D = 512;
constexpr int S = 2048;
constexpr int R = 64;
constexpr int KTOP = 16;
constexpr int NT = 4;    // tokens per block in score kernel
constexpr int NR = 16;   // rows per block in qk kernel
constexpr int NI = 4;    // rows per block in pscore kernel
constexpr int CAP = 256; // bin capacity per (b,slot); overflow -> atomic fallback

__device__ __forceinline__ float signf(float v) {
    return (v > 0.f) ? 1.f : ((v < 0.f) ? -1.f : 0.f);
}

// Exact top-16 by |value| (ties -> lower index) over a wave-private LDS row of S
// floats. Result: lane k (k<16) gets myg = signed value, myj = index, in exact
// descending (|v|, -j) order. Row contents are preserved on the fast path.
__device__ __forceinline__ void topk16_row(float* __restrict__ row,
                                           unsigned long long* __restrict__ cand,
                                           int lane, float& myg, int& myj) {
    const float4* p4 = (const float4*)row;
    // Phase 1: per-lane abs max over 32 elements
    float lmax = 0.f;
#pragma unroll
    for (int i = 0; i < 8; i++) {
        float4 v = p4[lane + 64 * i];
        lmax = fmaxf(lmax, fmaxf(fmaxf(fabsf(v.x), fabsf(v.y)),
                                 fmaxf(fabsf(v.z), fabsf(v.w))));
    }
    // Phase 2: bitonic sort (descending) of 64 lane maxes; t = 16th largest
    {
        float v = lmax;
#pragma unroll
        for (int size = 2; size <= 64; size <<= 1) {
#pragma unroll
            for (int stride = size >> 1; stride > 0; stride >>= 1) {
                float o = __shfl_xor(v, stride, 64);
                bool takeMax = ((lane & size) == 0) == ((lane & stride) == 0);
                v = takeMax ? fmaxf(v, o) : fminf(v, o);
            }
        }
        lmax = __shfl(v, 15);
    }
    float t = lmax;
    // Phase 3: count candidates with |v| >= t, prefix-sum, compact into cand[]
    int cnt = 0;
#pragma unroll
    for (int i = 0; i < 8; i++) {
        float4 v = p4[lane + 64 * i];
        cnt += (fabsf(v.x) >= t) + (fabsf(v.y) >= t) +
               (fabsf(v.z) >= t) + (fabsf(v.w) >= t);
    }
    int off = cnt;
#pragma unroll
    for (int d = 1; d < 64; d <<= 1) {
        int o = __shfl_up(off, d, 64);
        if (lane >= d) off += o;
    }
    int total = __shfl(off, 63);
    int base = off - cnt;

    if (total <= 64) {
        int pos = base;
#pragma unroll
        for (int i = 0; i < 8; i++) {
            float4 v = p4[lane + 64 * i];
            int jb = 4 * (lane + 64 * i);
            float c[4] = {v.x, v.y, v.z, v.w};
#pragma unroll
            for (int cc = 0; cc < 4; cc++) {
                if (fabsf(c[cc]) >= t) {
                    unsigned ab = __float_as_uint(c[cc]) & 0x7fffffffu;
                    cand[pos++] = ((unsigned long long)ab << 11) |
                                  (unsigned)(2047 - (jb + cc));
                }
            }
        }
        // Phase 4: bitonic sort (descending) of up to 64 u64 keys
        unsigned long long key = (lane < total) ? cand[lane] : 0ull;
#pragma unroll
        for (int size = 2; size <= 64; size <<= 1) {
#pragma unroll
            for (int stride = size >> 1; stride > 0; stride >>= 1) {
                unsigned long long o = __shfl_xor((long long)key, stride, 64);
                bool takeMax = ((lane & size) == 0) == ((lane & stride) == 0);
                key = (takeMax == (key > o)) ? key : o;
            }
        }
        myg = 0.f; myj = 0;
        if (lane < KTOP) {
            myj = 2047 - (int)(key & 2047ull);
            myg = row[myj];
        }
    } else {
        // Fallback (rare): 16 rounds of full-row argmax with removal
        myg = 0.f; myj = 0;
        for (int k = 0; k < KTOP; k++) {
            float bv = -1.f, bs = 0.f; int bj = 0;
#pragma unroll
            for (int i = 0; i < 8; i++) {
                float4 v = p4[lane + 64 * i];
                int jb = 4 * (lane + 64 * i);
                { float a = fabsf(v.x); if (a > bv) { bv = a; bs = v.x; bj = jb; } }
                { float a = fabsf(v.y); if (a > bv) { bv = a; bs = v.y; bj = jb + 1; } }
                { float a = fabsf(v.z); if (a > bv) { bv = a; bs = v.z; bj = jb + 2; } }
                { float a = fabsf(v.w); if (a > bv) { bv = a; bs = v.w; bj = jb + 3; } }
            }
#pragma unroll
            for (int off2 = 32; off2 > 0; off2 >>= 1) {
                float ov = __shfl_xor(bv, off2, 64);
                float os = __shfl_xor(bs, off2, 64);
                int   oj = __shfl_xor(bj, off2, 64);
                if (ov > bv || (ov == bv && oj < bj)) { bv = ov; bs = os; bj = oj; }
            }
            if (lane == k) { myg = bs; myj = bj; }
            if (lane == 0) row[bj] = 0.f;
        }
    }
}
} // namespace

// ---------- state init: state_ws[b][s] = sign * softmax(|init_state|) ----------
__global__ void k_init_state(const float* __restrict__ init_state,
                             float* __restrict__ state_ws) {
    int b = blockIdx.x;
    int tid = threadIdx.x;
    __shared__ float red[256];
    float m = -1e30f;
    for (int s = tid; s < S; s += 256) m = fmaxf(m, fabsf(init_state[s]));
    red[tid] = m; __syncthreads();
    for (int off = 128; off > 0; off >>= 1) {
        if (tid < off) red[tid] = fmaxf(red[tid], red[tid + off]);
        __syncthreads();
    }
    m = red[0]; __syncthreads();
    float sum = 0.f;
    for (int s = tid; s < S; s += 256) sum += expf(fabsf(init_state[s]) - m);
    red[tid] = sum; __syncthreads();
    for (int off = 128; off > 0; off >>= 1) {
        if (tid < off) red[tid] += red[tid + off];
        __syncthreads();
    }
    float inv = 1.0f / red[0];
    for (int s = tid; s < S; s += 256) {
        float v = init_state[s];
        state_ws[(size_t)b * S + s] = signf(v) * expf(fabsf(v) - m) * inv;
    }
}

// ---------- val broadcast init: val1[b][s][:] = unit_norm(init_val[s]) ----------
__global__ void k_bcast(const float* __restrict__ init_val,
                        float* __restrict__ val1) {
    int wv = threadIdx.x >> 6;
    int lane = threadIdx.x & 63;
    int blk = ((blockIdx.x & 7) << 9) | (blockIdx.x >> 3);  // XCD k <-> b=k
    int row = blk * 4 + wv;               // row = b*S + s
    int s = row & (S - 1);
    const float4* src = (const float4*)(init_val + (size_t)s * D);
    float4 v0 = src[lane], v1 = src[lane + 64];
    float ss = v0.x * v0.x + v0.y * v0.y + v0.z * v0.z + v0.w * v0.w
             + v1.x * v1.x + v1.y * v1.y + v1.z * v1.z + v1.w * v1.w;
#pragma unroll
    for (int off = 32; off > 0; off >>= 1) ss += __shfl_xor(ss, off, 64);
    float sc = 1.0f / (sqrtf(ss) + 1e-6f);
    v0.x *= sc; v0.y *= sc; v0.z *= sc; v0.w *= sc;
    v1.x *= sc; v1.y *= sc; v1.z *= sc; v1.w *= sc;
    float4* dst = (float4*)(val1 + (size_t)row * D);
    dst[lane] = v0; dst[lane + 64] = v1;
}

// ---------- score stage: route scores -> per-wave topk -> bin lists ----------
// LDS diet: no xs staging (x read at wave-uniform addresses in the xr stage,
// re-read coalesced for xinv/fallback); red4 reduction buffer overlaid with
// cand (live ranges separated by barriers). 37.9 KB -> 4 blocks/CU.
__global__ void __launch_bounds__(256) k_score(const float* __restrict__ x,
                                               const float* __restrict__ route_a,
                                               const float* __restrict__ route_b,
                                               float* __restrict__ val1,
                                               float* __restrict__ state_ws,
                                               float* __restrict__ coef,
                                               int* __restrict__ bincount,
                                               int* __restrict__ binlist) {
    __shared__ __align__(16) float sc[NT][S];     // 32 KB
    __shared__ __align__(16) float xr[NT][R];     // 1 KB
    __shared__ __align__(16) char umem[4096];     // 4 KB: red4 then cand
    float (*red4)[256] = (float(*)[256])umem;
    unsigned long long (*cand)[64] = (unsigned long long(*)[64])umem;

    int tid = threadIdx.x;
    int lane = tid & 63, wv = tid >> 6;
    int blk = ((blockIdx.x & 7) << 9) | (blockIdx.x >> 3);  // XCD k <-> b=k
    int tb = blk * NT;              // global token base (block never straddles b)
    int b = tb >> 11;               // T = 2048
    int t0 = tb & (T - 1);

    // xr = x . route_a  (x via wave-uniform loads; no LDS staging)
    {
        int r = lane, grp = wv;
        const float* xrow = x + (size_t)tb * D;
        float acc[NT] = {0.f, 0.f, 0.f, 0.f};
        for (int d0 = grp * 128; d0 < grp * 128 + 128; d0 += 4) {
            float a0 = route_a[(size_t)(d0 + 0) * R + r];
            float a1 = route_a[(size_t)(d0 + 1) * R + r];
            float a2 = route_a[(size_t)(d0 + 2) * R + r];
            float a3 = route_a[(size_t)(d0 + 3) * R + r];
#pragma unroll
            for (int tt = 0; tt < NT; tt++) {
                float4 xv = *(const float4*)(xrow + (size_t)tt * D + d0);
                acc[tt] += xv.x * a0 + xv.y * a1 + xv.z * a2 + xv.w * a3;
            }
        }
#pragma unroll
        for (int tt = 0; tt < NT; tt++) red4[tt][tid] = acc[tt];
        __syncthreads();
        {
            int tt2 = tid >> 6, r2 = tid & 63;
            xr[tt2][r2] = red4[tt2][r2] + red4[tt2][64 + r2] +
                          red4[tt2][128 + r2] + red4[tt2][192 + r2];
        }
        __syncthreads();
    }

    // scores = xr . route_b  (float4 over s)
    {
        const float4* rb4 = (const float4*)route_b;
#pragma unroll
        for (int i = 0; i < 2; i++) {
            int j4 = tid + 256 * i;
            float4 acc[NT];
#pragma unroll
            for (int tt = 0; tt < NT; tt++) acc[tt] = make_float4(0.f, 0.f, 0.f, 0.f);
            for (int r0 = 0; r0 < R; r0 += 4) {
                float4 xv[NT];
#pragma unroll
                for (int tt = 0; tt < NT; tt++) xv[tt] = *(const float4*)&xr[tt][r0];
#define SCORE_STEP(dr, comp)                                                   \
                {                                                              \
                    float4 bv = rb4[(size_t)(r0 + dr) * (S / 4) + j4];         \
                    _Pragma("unroll")                                          \
                    for (int tt = 0; tt < NT; tt++) {                          \
                        float c = xv[tt].comp;                                 \
                        acc[tt].x += c * bv.x; acc[tt].y += c * bv.y;          \
                        acc[tt].z += c * bv.z; acc[tt].w += c * bv.w;          \
                    }                                                          \
                }
                SCORE_STEP(0, x) SCORE_STEP(1, y) SCORE_STEP(2, z) SCORE_STEP(3, w)
#undef SCORE_STEP
            }
#pragma unroll
            for (int tt = 0; tt < NT; tt++)
                ((float4*)&sc[tt][0])[j4] = acc[tt];
        }
    }
    __syncthreads();

    // ---- per-wave from here: wave wv owns token tt = wv ----
    int tt = wv;
    int tloc = t0 + tt;
    int tglob = tb + tt;

    // x inverse norm (per wave, coalesced global re-read; row is L2-hot)
    float xinv;
    {
        const float4* xg = (const float4*)(x + (size_t)tglob * D);
        float4 x0 = xg[lane], x1 = xg[lane + 64];
        float ss = x0.x * x0.x + x0.y * x0.y + x0.z * x0.z + x0.w * x0.w
                 + x1.x * x1.x + x1.y * x1.y + x1.z * x1.z + x1.w * x1.w;
#pragma unroll
        for (int off = 32; off > 0; off >>= 1) ss += __shfl_xor(ss, off, 64);
        xinv = 1.0f / (sqrtf(ss) + 1e-6f);
    }

    float myg; int myj;
    topk16_row(&sc[tt][0], &cand[wv][0], lane, myg, myj);

    // signed-abs-softmax over the 16 winners (lane k holds winner k)
    float m = __shfl(fabsf(myg), 0);
    float e = (lane < KTOP) ? expf(fabsf(myg) - m) : 0.f;
    float esum = e;
#pragma unroll
    for (int off = 8; off > 0; off >>= 1) esum += __shfl_xor(esum, off, 64);
    esum = __shfl(esum, 0);
    float w = signf(myg) * e / esum;
    float coefv = w * xinv;

    unsigned long long ovf = 0ull;
    int pos = 0;
    if (lane < KTOP) {
        float sp = (myg > 20.f) ? myg : log1pf(expf(myg));
        atomicAdd(&state_ws[(size_t)b * S + myj], sp);
        pos = atomicAdd(&bincount[(size_t)b * S + myj], 1);
        if (pos < CAP) {
            binlist[((size_t)b * S + myj) * CAP + pos] = (tloc << 4) | lane;
            coef[(size_t)tglob * KTOP + lane] = coefv;
        }
    }
    ovf = __ballot(lane < KTOP && pos >= CAP);
    while (ovf) {   // overflow fallback (essentially never)
        int src = __ffsll(ovf) - 1;
        int j = __shfl(myj, src);
        float c = __shfl(coefv, src);
        float* dst = val1 + ((size_t)b * S + j) * D;
        const float* xrow = x + (size_t)tglob * D;
#pragma unroll
        for (int i = 0; i < 8; i++)
            atomicAdd(&dst[lane + 64 * i], c * xrow[lane + 64 * i]);
        ovf &= ovf - 1;
    }
}

// ---------- accumulate bins: val1[row] = unit_norm(val1[row] + sum c*x) ----------
__global__ void __launch_bounds__(256) k_accum(const float* __restrict__ x,
                                               const float* __restrict__ coef,
                                               const int* __restrict__ bincount,
                                               const int* __restrict__ binlist,
                                               float* __restrict__ val1) {
    int lane = threadIdx.x & 63, wv = threadIdx.x >> 6;
    int blk = ((blockIdx.x & 7) << 9) | (blockIdx.x >> 3);  // XCD k <-> b=k
    int row = blk * 4 + wv;             // row = b*S + s
    int b = row >> 11;                  // S = 2048
    float4* vp4 = (float4*)(val1 + (size_t)row * D);
    float4 a0 = vp4[lane], a1 = vp4[lane + 64];
    int n = bincount[row]; if (n > CAP) n = CAP;
    const int* lp = binlist + (size_t)row * CAP;
    for (int base = 0; base < n; base += 64) {
        int mm = n - base; if (mm > 64) mm = 64;
        int ent = 0; float cc = 0.f;
        if (lane < mm) {
            ent = lp[base + lane];
            cc = coef[((size_t)b * T + (ent >> 4)) * KTOP + (ent & 15)];
        }
        for (int k = 0; k < mm; k++) {
            int e2 = __shfl(ent, k);
            float c = __shfl(cc, k);
            const float4* xp4 = (const float4*)(x + ((size_t)b * T + (e2 >> 4)) * D);
            float4 v0 = xp4[lane], v1 = xp4[lane + 64];
            a0.x += c * v0.x; a0.y += c * v0.y; a0.z += c * v0.z; a0.w += c * v0.w;
            a1.x += c * v1.x; a1.y += c * v1.y; a1.z += c * v1.z; a1.w += c * v1.w;
        }
    }
    float ss = a0.x * a0.x + a0.y * a0.y + a0.z * a0.z + a0.w * a0.w
             + a1.x * a1.x + a1.y * a1.y + a1.z * a1.z + a1.w * a1.w;
#pragma unroll
    for (int off = 32; off > 0; off >>= 1) ss += __shfl_xor(ss, off, 64);
    float sc = 1.0f / (sqrtf(ss) + 1e-6f);
    a0.x *= sc; a0.y *= sc; a0.z *= sc; a0.w *= sc;
    a1.x *= sc; a1.y *= sc; a1.z *= sc; a1.w *= sc;
    vp4[lane] = a0; vp4[lane + 64] = a1;
}

// ---------- state finalize: signed-abs-softmax -> out[...,0] ----------
__global__ void k_state_final(const float* __restrict__ state_ws,
                              float* __restrict__ out) {
    int b = blockIdx.x;
    int tid = threadIdx.x;
    __shared__ float red[256];
    const float* sp = state_ws + (size_t)b * S;
    float m = -1e30f;
    for (int s = tid; s < S; s += 256) m = fmaxf(m, fabsf(sp[s]));
    red[tid] = m; __syncthreads();
    for (int off = 128; off > 0; off >>= 1) {
        if (tid < off) red[tid] = fmaxf(red[tid], red[tid + off]);
        __syncthreads();
    }
    m = red[0]; __syncthreads();
    float sum = 0.f;
    for (int s = tid; s < S; s += 256) sum += expf(fabsf(sp[s]) - m);
    red[tid] = sum; __syncthreads();
    for (int off = 128; off > 0; off >>= 1) {
        if (tid < off) red[tid] += red[tid + off];
        __syncthreads();
    }
    float inv = 1.0f / red[0];
    for (int s = tid; s < S; s += 256) {
        float v = sp[s];
        out[((size_t)b * S + s) * (D + 1)] = signf(v) * expf(fabsf(v) - m) * inv;
    }
}

// ---------- q / kT projections ----------
__global__ void __launch_bounds__(256) k_qk(const float* __restrict__ val1,
                                            const float* __restrict__ pair_a,
                                            const float* __restrict__ pair_b,
                                            float* __restrict__ q,
                                            float* __restrict__ kkT) {
    __shared__ __align__(16) float vrow[NR][D];   // 32 KB
    __shared__ float redq[256];
    __shared__ float redk[256];
    int tid = threadIdx.x;
    int blk = ((blockIdx.x & 7) << 7) | (blockIdx.x >> 3);  // XCD k <-> b=k
    int rowbase = blk * NR;           // = b*S + sbase (never straddles b)
    int b = rowbase >> 11;
    int sbase = rowbase & (S - 1);
    {
        const float4* gv = (const float4*)(val1 + (size_t)rowbase * D);
        float4* lv = (float4*)&vrow[0][0];
        for (int i = tid; i < NR * D / 4; i += 256) lv[i] = gv[i];
    }
    __syncthreads();
    int r = tid & 63, grp = tid >> 6;
    float accq[NR], acck[NR];
#pragma unroll
    for (int rr = 0; rr < NR; rr++) { accq[rr] = 0.f; acck[rr] = 0.f; }
    for (int d0 = grp * 128; d0 < grp * 128 + 128; d0 += 4) {
#pragma unroll
        for (int dd = 0; dd < 4; dd++) {
            float a  = pair_a[(size_t)(d0 + dd) * R + r];
            float bb = pair_b[(size_t)(d0 + dd) * R + r];
#pragma unroll
            for (int rr = 0; rr < NR; rr++) {
                float v = vrow[rr][d0 + dd];
                accq[rr] += v * a;
                acck[rr] += v * bb;
            }
        }
    }
    for (int rr = 0; rr < NR; rr++) {
        redq[tid] = accq[rr]; redk[tid] = acck[rr];
        __syncthreads();
        if (tid < 64) {
            float qv = redq[tid] + redq[tid + 64] + redq[tid + 128] + redq[tid + 192];
            float kv = redk[tid] + redk[tid + 64] + redk[tid + 128] + redk[tid + 192];
            q[(size_t)(rowbase + rr) * R + tid] = qv;
            kkT[((size_t)b * R + tid) * S + (sbase + rr)] = kv;
        }
        __syncthreads();
    }
}

// ---------- pscore: p = q.kT (float4), per-wave topk -> eidx/ew ----------
__global__ void __launch_bounds__(256) k_pscore(const float* __restrict__ q,
                                                const float* __restrict__ kkT,
                                                int* __restrict__ eidx,
                                                float* __restrict__ ew_g) {
    __shared__ __align__(16) float prow[NI][S];   // 32 KB
    __shared__ __align__(16) float qrow[NI][R];
    __shared__ unsigned long long cand[NI][64];   // 2 KB

    int tid = threadIdx.x;
    int lane = tid & 63, wv = tid >> 6;
    int blk = ((blockIdx.x & 7) << 9) | (blockIdx.x >> 3);  // XCD k <-> b=k
    int ibase = blk * NI;            // global row base (never straddles b)
    int b = ibase >> 11;             // S = 2048

    {
        int rr = tid >> 6, r = tid & 63;
        qrow[rr][r] = q[(size_t)(ibase + rr) * R + r];
    }
    __syncthreads();

    // p rows (float4 over j; kkT slice reused by 4 rows)
    {
        const float4* kk4 = (const float4*)(kkT + (size_t)b * R * S);
#pragma unroll
        for (int i = 0; i < 2; i++) {
            int j4 = tid + 256 * i;
            float4 acc[NI];
#pragma unroll
            for (int rr = 0; rr < NI; rr++) acc[rr] = make_float4(0.f, 0.f, 0.f, 0.f);
            for (int r0 = 0; r0 < R; r0 += 4) {
                float4 qv[NI];
#pragma unroll
                for (int rr = 0; rr < NI; rr++) qv[rr] = *(const float4*)&qrow[rr][r0];
#define P_STEP(dr, comp)                                                       \
                {                                                              \
                    float4 kv = kk4[(size_t)(r0 + dr) * (S / 4) + j4];         \
                    _Pragma("unroll")                                          \
                    for (int rr = 0; rr < NI; rr++) {                          \
                        float c = qv[rr].comp;                                 \
                        acc[rr].x += c * kv.x; acc[rr].y += c * kv.y;          \
                        acc[rr].z += c * kv.z; acc[rr].w += c * kv.w;          \
                    }                                                          \
                }
                P_STEP(0, x) P_STEP(1, y) P_STEP(2, z) P_STEP(3, w)
#undef P_STEP
            }
#pragma unroll
            for (int rr = 0; rr < NI; rr++)
                ((float4*)&prow[rr][0])[j4] = acc[rr];
        }
    }
    __syncthreads();

    // ---- per-wave topk on row ibase + wv ----
    int row = ibase + wv;
    float myg; int myj;
    topk16_row(&prow[wv][0], &cand[wv][0], lane, myg, myj);

    float m = __shfl(fabsf(myg), 0);
    float e = (lane < KTOP) ? expf(fabsf(myg) - m) : 0.f;
    float esum = e;
#pragma unroll
    for (int off = 8; off > 0; off >>= 1) esum += __shfl_xor(esum, off, 64);
    esum = __shfl(esum, 0);
    float myw = signf(myg) * e / esum;

    if (lane < KTOP) {
        eidx[(size_t)row * KTOP + lane] = myj;
        ew_g[(size_t)row * KTOP + lane] = myw;
    }
}

// ---------- mix: gather neighbors, residual add, unit-norm, out[...,1:] ----------
__global__ void __launch_bounds__(256) k_mix(const int* __restrict__ eidx,
                                             const float* __restrict__ ew_g,
                                             const float* __restrict__ val1,
                                             float* __restrict__ out) {
    int lane = threadIdx.x & 63, wv = threadIdx.x >> 6;
    int blk = ((blockIdx.x & 7) << 9) | (blockIdx.x >> 3);  // XCD k <-> b=k
    int row = blk * 4 + wv;
    int b = row >> 11;

    int e_i = 0; float e_w = 0.f;
    if (lane < KTOP) {
        e_i = eidx[(size_t)row * KTOP + lane];
        e_w = ew_g[(size_t)row * KTOP + lane];
    }

    const float4* self4 = (const float4*)(val1 + (size_t)row * D);
    float4 a0 = self4[lane], a1 = self4[lane + 64];
#pragma unroll
    for (int k = 0; k < KTOP; k++) {
        int j = __shfl(e_i, k);
        float w = __shfl(e_w, k);
        const float4* nb4 = (const float4*)(val1 + ((size_t)b * S + j) * D);
        float4 v0 = nb4[lane], v1 = nb4[lane + 64];
        a0.x += w * v0.x; a0.y += w * v0.y; a0.z += w * v0.z; a0.w += w * v0.w;
        a1.x += w * v1.x; a1.y += w * v1.y; a1.z += w * v1.z; a1.w += w * v1.w;
    }
    float ss = a0.x * a0.x + a0.y * a0.y + a0.z * a0.z + a0.w * a0.w
             + a1.x * a1.x + a1.y * a1.y + a1.z * a1.z + a1.w * a1.w;
#pragma unroll
    for (int off = 32; off > 0; off >>= 1) ss += __shfl_xor(ss, off, 64);
    float sc = 1.0f / (sqrtf(ss) + 1e-6f);
    float* op = out + (size_t)row * (D + 1) + 1;
    int d0 = 4 * lane;
    op[d0 + 0] = a0.x * sc; op[d0 + 1] = a0.y * sc;
    op[d0 + 2] = a0.z * sc; op[d0 + 3] = a0.w * sc;
    op[256 + d0 + 0] = a1.x * sc; op[256 + d0 + 1] = a1.y * sc;
    op[256 + d0 + 2] = a1.z * sc; op[256 + d0 + 3] = a1.w * sc;
}

extern "C" void kernel_launch(void* const* d_in, const int* in_sizes, int n_in,
                              void* d_out, int out_size, void* d_ws, size_t ws_size,
                              hipStream_t stream) {
    (void)in_sizes; (void)n_in; (void)out_size; (void)ws_size;
    const float* x          = (const float*)d_in[0];
    const float* init_state = (const float*)d_in[1];
    const float* init_val   = (const float*)d_in[2];
    const float* route_a    = (const float*)d_in[3];
    const float* route_b    = (const float*)d_in[4];
    const float* pair_a     = (const float*)d_in[5];
    const float* pair_b     = (const float*)d_in[6];
    float* out = (float*)d_out;

    float* ws       = (float*)d_ws;
    float* val1     = ws;                             // B*S*D
    float* q        = val1 + (size_t)B * S * D;       // B*S*R
    float* kkT      = q    + (size_t)B * S * R;       // B*R*S
    float* state_ws = kkT  + (size_t)B * R * S;       // B*S
    float* coef     = state_ws + (size_t)B * S;       // B*T*K
    int*   bincount = (int*)(coef + (size_t)B * T * KTOP);   // B*S
    int*   binlist  = bincount + (size_t)B * S;              // B*S*CAP
    // eidx/ew reuse binlist space (binlist dead after k_accum)
    int*   eidx     = binlist;                               // B*S*K
    float* ew       = (float*)(binlist + (size_t)B * S * KTOP);  // B*S*K

    hipMemsetAsync(bincount, 0, (size_t)B * S * sizeof(int), stream);
    hipLaunchKernelGGL(k_init_state, dim3(B), dim3(256), 0, stream, init_state, state_ws);
    hipLaunchKernelGGL(k_bcast, dim3(B * S / 4), dim3(256), 0, stream, init_val, val1);
    hipLaunchKernelGGL(k_score, dim3(B * T / NT), dim3(256), 0, stream,
                       x, route_a, route_b, val1, state_ws, coef, bincount, binlist);
    hipLaunchKernelGGL(k_state_final, dim3(B), dim3(256), 0, stream, state_ws, out);
    hipLaunchKernelGGL(k_accum, dim3(B * S / 4), dim3(256), 0, stream,
                       x, coef, bincount, binlist, val1);
    hipLaunchKernelGGL(k_qk, dim3(B * S / NR), dim3(256), 0, stream,
                       val1, pair_a, pair_b, q, kkT);
    hipLaunchKernelGGL(k_pscore, dim3(B * S / NI), dim3(256), 0, stream,
                       q, kkT, eidx, ew);
    hipLaunchKernelGGL(k_mix, dim3(B * S / 4), dim3(256), 0, stream,
                       eidx, ew, val1, out);
}

// Round 2
// 433.227 us; speedup vs baseline: 1.1995x; 1.1108x over previous
//
#include <hip/hip_runtime.h>
#include <cmath>

namespace {
constexpr int B = 8;
constexpr int T = 2048;
constexpr int D = 512;
constexpr int S = 2048;
constexpr int R = 64;
constexpr int KTOP = 16;
constexpr int NT = 4;    // tokens per block in score kernel
constexpr int NR = 16;   // rows per block in qk kernel
constexpr int NI = 8;    // rows per block in pscore kernel (512 threads)
constexpr int CAP = 256; // bin capacity per (b,slot); overflow -> atomic fallback

__device__ __forceinline__ float signf(float v) {
    return (v > 0.f) ? 1.f : ((v < 0.f) ? -1.f : 0.f);
}

// Exact top-16 by |value| (ties -> lower index) over a wave-private LDS row of S
// floats. Result: lane k (k<16) gets myg = signed value, myj = index, in exact
// descending (|v|, -j) order. Row contents are preserved on the fast path.
__device__ __forceinline__ void topk16_row(float* __restrict__ row,
                                           unsigned long long* __restrict__ cand,
                                           int lane, float& myg, int& myj) {
    const float4* p4 = (const float4*)row;
    // Phase 1: per-lane abs max over 32 elements
    float lmax = 0.f;
#pragma unroll
    for (int i = 0; i < 8; i++) {
        float4 v = p4[lane + 64 * i];
        lmax = fmaxf(lmax, fmaxf(fmaxf(fabsf(v.x), fabsf(v.y)),
                                 fmaxf(fabsf(v.z), fabsf(v.w))));
    }
    // Phase 2: bitonic sort (descending) of 64 lane maxes; t = 16th largest
    {
        float v = lmax;
#pragma unroll
        for (int size = 2; size <= 64; size <<= 1) {
#pragma unroll
            for (int stride = size >> 1; stride > 0; stride >>= 1) {
                float o = __shfl_xor(v, stride, 64);
                bool takeMax = ((lane & size) == 0) == ((lane & stride) == 0);
                v = takeMax ? fmaxf(v, o) : fminf(v, o);
            }
        }
        lmax = __shfl(v, 15);
    }
    float t = lmax;
    // Phase 3: count candidates with |v| >= t, prefix-sum, compact into cand[]
    int cnt = 0;
#pragma unroll
    for (int i = 0; i < 8; i++) {
        float4 v = p4[lane + 64 * i];
        cnt += (fabsf(v.x) >= t) + (fabsf(v.y) >= t) +
               (fabsf(v.z) >= t) + (fabsf(v.w) >= t);
    }
    int off = cnt;
#pragma unroll
    for (int d = 1; d < 64; d <<= 1) {
        int o = __shfl_up(off, d, 64);
        if (lane >= d) off += o;
    }
    int total = __shfl(off, 63);
    int base = off - cnt;

    if (total <= 64) {
        int pos = base;
#pragma unroll
        for (int i = 0; i < 8; i++) {
            float4 v = p4[lane + 64 * i];
            int jb = 4 * (lane + 64 * i);
            float c[4] = {v.x, v.y, v.z, v.w};
#pragma unroll
            for (int cc = 0; cc < 4; cc++) {
                if (fabsf(c[cc]) >= t) {
                    unsigned ab = __float_as_uint(c[cc]) & 0x7fffffffu;
                    cand[pos++] = ((unsigned long long)ab << 11) |
                                  (unsigned)(2047 - (jb + cc));
                }
            }
        }
        // Phase 4: bitonic sort (descending) of up to 64 u64 keys
        unsigned long long key = (lane < total) ? cand[lane] : 0ull;
#pragma unroll
        for (int size = 2; size <= 64; size <<= 1) {
#pragma unroll
            for (int stride = size >> 1; stride > 0; stride >>= 1) {
                unsigned long long o = __shfl_xor((long long)key, stride, 64);
                bool takeMax = ((lane & size) == 0) == ((lane & stride) == 0);
                key = (takeMax == (key > o)) ? key : o;
            }
        }
        myg = 0.f; myj = 0;
        if (lane < KTOP) {
            myj = 2047 - (int)(key & 2047ull);
            myg = row[myj];
        }
    } else {
        // Fallback (rare): 16 rounds of full-row argmax with removal
        myg = 0.f; myj = 0;
        for (int k = 0; k < KTOP; k++) {
            float bv = -1.f, bs = 0.f; int bj = 0;
#pragma unroll
            for (int i = 0; i < 8; i++) {
                float4 v = p4[lane + 64 * i];
                int jb = 4 * (lane + 64 * i);
                { float a = fabsf(v.x); if (a > bv) { bv = a; bs = v.x; bj = jb; } }
                { float a = fabsf(v.y); if (a > bv) { bv = a; bs = v.y; bj = jb + 1; } }
                { float a = fabsf(v.z); if (a > bv) { bv = a; bs = v.z; bj = jb + 2; } }
                { float a = fabsf(v.w); if (a > bv) { bv = a; bs = v.w; bj = jb + 3; } }
            }
#pragma unroll
            for (int off2 = 32; off2 > 0; off2 >>= 1) {
                float ov = __shfl_xor(bv, off2, 64);
                float os = __shfl_xor(bs, off2, 64);
                int   oj = __shfl_xor(bj, off2, 64);
                if (ov > bv || (ov == bv && oj < bj)) { bv = ov; bs = os; bj = oj; }
            }
            if (lane == k) { myg = bs; myj = bj; }
            if (lane == 0) row[bj] = 0.f;
        }
    }
}
} // namespace

// ---------- state init: state_ws[b][s] = sign * softmax(|init_state|) ----------
__global__ void k_init_state(const float* __restrict__ init_state,
                             float* __restrict__ state_ws) {
    int b = blockIdx.x;
    int tid = threadIdx.x;
    __shared__ float red[256];
    float m = -1e30f;
    for (int s = tid; s < S; s += 256) m = fmaxf(m, fabsf(init_state[s]));
    red[tid] = m; __syncthreads();
    for (int off = 128; off > 0; off >>= 1) {
        if (tid < off) red[tid] = fmaxf(red[tid], red[tid + off]);
        __syncthreads();
    }
    m = red[0]; __syncthreads();
    float sum = 0.f;
    for (int s = tid; s < S; s += 256) sum += expf(fabsf(init_state[s]) - m);
    red[tid] = sum; __syncthreads();
    for (int off = 128; off > 0; off >>= 1) {
        if (tid < off) red[tid] += red[tid + off];
        __syncthreads();
    }
    float inv = 1.0f / red[0];
    for (int s = tid; s < S; s += 256) {
        float v = init_state[s];
        state_ws[(size_t)b * S + s] = signf(v) * expf(fabsf(v) - m) * inv;
    }
}

// ---------- val broadcast init: val1[b][s][:] = unit_norm(init_val[s]) ----------
__global__ void k_bcast(const float* __restrict__ init_val,
                        float* __restrict__ val1) {
    int wv = threadIdx.x >> 6;
    int lane = threadIdx.x & 63;
    int blk = ((blockIdx.x & 7) << 9) | (blockIdx.x >> 3);  // XCD k <-> b=k
    int row = blk * 4 + wv;               // row = b*S + s
    int s = row & (S - 1);
    const float4* src = (const float4*)(init_val + (size_t)s * D);
    float4 v0 = src[lane], v1 = src[lane + 64];
    float ss = v0.x * v0.x + v0.y * v0.y + v0.z * v0.z + v0.w * v0.w
             + v1.x * v1.x + v1.y * v1.y + v1.z * v1.z + v1.w * v1.w;
#pragma unroll
    for (int off = 32; off > 0; off >>= 1) ss += __shfl_xor(ss, off, 64);
    float sc = 1.0f / (sqrtf(ss) + 1e-6f);
    v0.x *= sc; v0.y *= sc; v0.z *= sc; v0.w *= sc;
    v1.x *= sc; v1.y *= sc; v1.z *= sc; v1.w *= sc;
    float4* dst = (float4*)(val1 + (size_t)row * D);
    dst[lane] = v0; dst[lane + 64] = v1;
}

// ---------- score stage: route scores -> per-wave topk -> bin lists ----------
// LDS budget 37.9 KB -> 4 blocks/CU. xs (8 KB, live in xr stage only) is
// overlaid on sc (32 KB, live after xr stage); red4 overlaid with cand.
__global__ void __launch_bounds__(256) k_score(const float* __restrict__ x,
                                               const float* __restrict__ route_a,
                                               const float* __restrict__ route_b,
                                               float* __restrict__ val1,
                                               float* __restrict__ state_ws,
                                               float* __restrict__ coef,
                                               int* __restrict__ bincount,
                                               int* __restrict__ binlist) {
    __shared__ __align__(16) char smem[NT * S * 4]; // 32 KB: xs then sc
    __shared__ __align__(16) float xr[NT][R];       // 1 KB
    __shared__ __align__(16) char umem[4096];       // 4 KB: red4 then cand
    float (*sc)[S] = (float(*)[S])smem;
    float (*xs)[D] = (float(*)[D])smem;             // overlay (xr stage only)
    float (*red4)[256] = (float(*)[256])umem;
    unsigned long long (*cand)[64] = (unsigned long long(*)[64])umem;

    int tid = threadIdx.x;
    int lane = tid & 63, wv = tid >> 6;
    int blk = ((blockIdx.x & 7) << 9) | (blockIdx.x >> 3);  // XCD k <-> b=k
    int tb = blk * NT;              // global token base (block never straddles b)
    int b = tb >> 11;               // T = 2048
    int t0 = tb & (T - 1);

    // load 4 x rows into LDS (vectorized)
    {
        const float4* xg = (const float4*)(x + (size_t)tb * D);
        float4* xls = (float4*)&xs[0][0];
        xls[tid] = xg[tid];
        xls[tid + 256] = xg[tid + 256];
    }
    __syncthreads();

    // xr = x . route_a  (b128 LDS broadcast reads of xs)
    {
        int r = lane, grp = wv;
        float acc[NT] = {0.f, 0.f, 0.f, 0.f};
        for (int d0 = grp * 128; d0 < grp * 128 + 128; d0 += 4) {
            float a0 = route_a[(size_t)(d0 + 0) * R + r];
            float a1 = route_a[(size_t)(d0 + 1) * R + r];
            float a2 = route_a[(size_t)(d0 + 2) * R + r];
            float a3 = route_a[(size_t)(d0 + 3) * R + r];
#pragma unroll
            for (int tt = 0; tt < NT; tt++) {
                float4 xv = *(const float4*)&xs[tt][d0];
                acc[tt] += xv.x * a0 + xv.y * a1 + xv.z * a2 + xv.w * a3;
            }
        }
#pragma unroll
        for (int tt = 0; tt < NT; tt++) red4[tt][tid] = acc[tt];
        __syncthreads();
        {
            int tt2 = tid >> 6, r2 = tid & 63;
            xr[tt2][r2] = red4[tt2][r2] + red4[tt2][64 + r2] +
                          red4[tt2][128 + r2] + red4[tt2][192 + r2];
        }
        __syncthreads();   // xs dead from here; sc may be written
    }

    // scores = xr . route_b  (float4 over s)
    {
        const float4* rb4 = (const float4*)route_b;
#pragma unroll
        for (int i = 0; i < 2; i++) {
            int j4 = tid + 256 * i;
            float4 acc[NT];
#pragma unroll
            for (int tt = 0; tt < NT; tt++) acc[tt] = make_float4(0.f, 0.f, 0.f, 0.f);
            for (int r0 = 0; r0 < R; r0 += 4) {
                float4 xv[NT];
#pragma unroll
                for (int tt = 0; tt < NT; tt++) xv[tt] = *(const float4*)&xr[tt][r0];
#define SCORE_STEP(dr, comp)                                                   \
                {                                                              \
                    float4 bv = rb4[(size_t)(r0 + dr) * (S / 4) + j4];         \
                    _Pragma("unroll")                                          \
                    for (int tt = 0; tt < NT; tt++) {                          \
                        float c = xv[tt].comp;                                 \
                        acc[tt].x += c * bv.x; acc[tt].y += c * bv.y;          \
                        acc[tt].z += c * bv.z; acc[tt].w += c * bv.w;          \
                    }                                                          \
                }
                SCORE_STEP(0, x) SCORE_STEP(1, y) SCORE_STEP(2, z) SCORE_STEP(3, w)
#undef SCORE_STEP
            }
#pragma unroll
            for (int tt = 0; tt < NT; tt++)
                ((float4*)&sc[tt][0])[j4] = acc[tt];
        }
    }
    __syncthreads();

    // ---- per-wave from here: wave wv owns token tt = wv ----
    int tt = wv;
    int tloc = t0 + tt;
    int tglob = tb + tt;

    // x inverse norm (coalesced global re-read; row is L2-hot)
    float xinv;
    {
        const float4* xg = (const float4*)(x + (size_t)tglob * D);
        float4 x0 = xg[lane], x1 = xg[lane + 64];
        float ss = x0.x * x0.x + x0.y * x0.y + x0.z * x0.z + x0.w * x0.w
                 + x1.x * x1.x + x1.y * x1.y + x1.z * x1.z + x1.w * x1.w;
#pragma unroll
        for (int off = 32; off > 0; off >>= 1) ss += __shfl_xor(ss, off, 64);
        xinv = 1.0f / (sqrtf(ss) + 1e-6f);
    }

    float myg; int myj;
    topk16_row(&sc[tt][0], &cand[wv][0], lane, myg, myj);

    // signed-abs-softmax over the 16 winners (lane k holds winner k)
    float m = __shfl(fabsf(myg), 0);
    float e = (lane < KTOP) ? expf(fabsf(myg) - m) : 0.f;
    float esum = e;
#pragma unroll
    for (int off = 8; off > 0; off >>= 1) esum += __shfl_xor(esum, off, 64);
    esum = __shfl(esum, 0);
    float w = signf(myg) * e / esum;
    float coefv = w * xinv;

    unsigned long long ovf = 0ull;
    int pos = 0;
    if (lane < KTOP) {
        float sp = (myg > 20.f) ? myg : log1pf(expf(myg));
        atomicAdd(&state_ws[(size_t)b * S + myj], sp);
        pos = atomicAdd(&bincount[(size_t)b * S + myj], 1);
        if (pos < CAP) {
            binlist[((size_t)b * S + myj) * CAP + pos] = (tloc << 4) | lane;
            coef[(size_t)tglob * KTOP + lane] = coefv;
        }
    }
    ovf = __ballot(lane < KTOP && pos >= CAP);
    while (ovf) {   // overflow fallback (essentially never)
        int src = __ffsll(ovf) - 1;
        int j = __shfl(myj, src);
        float c = __shfl(coefv, src);
        float* dst = val1 + ((size_t)b * S + j) * D;
        const float* xrow = x + (size_t)tglob * D;
#pragma unroll
        for (int i = 0; i < 8; i++)
            atomicAdd(&dst[lane + 64 * i], c * xrow[lane + 64 * i]);
        ovf &= ovf - 1;
    }
}

// ---------- accumulate bins: val1[row] = unit_norm(val1[row] + sum c*x) ----------
__global__ void __launch_bounds__(256) k_accum(const float* __restrict__ x,
                                               const float* __restrict__ coef,
                                               const int* __restrict__ bincount,
                                               const int* __restrict__ binlist,
                                               float* __restrict__ val1) {
    int lane = threadIdx.x & 63, wv = threadIdx.x >> 6;
    int blk = ((blockIdx.x & 7) << 9) | (blockIdx.x >> 3);  // XCD k <-> b=k
    int row = blk * 4 + wv;             // row = b*S + s
    int b = row >> 11;                  // S = 2048
    float4* vp4 = (float4*)(val1 + (size_t)row * D);
    float4 a0 = vp4[lane], a1 = vp4[lane + 64];
    int n = bincount[row]; if (n > CAP) n = CAP;
    const int* lp = binlist + (size_t)row * CAP;
    for (int base = 0; base < n; base += 64) {
        int mm = n - base; if (mm > 64) mm = 64;
        int ent = 0; float cc = 0.f;
        if (lane < mm) {
            ent = lp[base + lane];
            cc = coef[((size_t)b * T + (ent >> 4)) * KTOP + (ent & 15)];
        }
        for (int k = 0; k < mm; k++) {
            int e2 = __shfl(ent, k);
            float c = __shfl(cc, k);
            const float4* xp4 = (const float4*)(x + ((size_t)b * T + (e2 >> 4)) * D);
            float4 v0 = xp4[lane], v1 = xp4[lane + 64];
            a0.x += c * v0.x; a0.y += c * v0.y; a0.z += c * v0.z; a0.w += c * v0.w;
            a1.x += c * v1.x; a1.y += c * v1.y; a1.z += c * v1.z; a1.w += c * v1.w;
        }
    }
    float ss = a0.x * a0.x + a0.y * a0.y + a0.z * a0.z + a0.w * a0.w
             + a1.x * a1.x + a1.y * a1.y + a1.z * a1.z + a1.w * a1.w;
#pragma unroll
    for (int off = 32; off > 0; off >>= 1) ss += __shfl_xor(ss, off, 64);
    float sc = 1.0f / (sqrtf(ss) + 1e-6f);
    a0.x *= sc; a0.y *= sc; a0.z *= sc; a0.w *= sc;
    a1.x *= sc; a1.y *= sc; a1.z *= sc; a1.w *= sc;
    vp4[lane] = a0; vp4[lane + 64] = a1;
}

// ---------- state finalize: signed-abs-softmax -> out[...,0] ----------
__global__ void k_state_final(const float* __restrict__ state_ws,
                              float* __restrict__ out) {
    int b = blockIdx.x;
    int tid = threadIdx.x;
    __shared__ float red[256];
    const float* sp = state_ws + (size_t)b * S;
    float m = -1e30f;
    for (int s = tid; s < S; s += 256) m = fmaxf(m, fabsf(sp[s]));
    red[tid] = m; __syncthreads();
    for (int off = 128; off > 0; off >>= 1) {
        if (tid < off) red[tid] = fmaxf(red[tid], red[tid + off]);
        __syncthreads();
    }
    m = red[0]; __syncthreads();
    float sum = 0.f;
    for (int s = tid; s < S; s += 256) sum += expf(fabsf(sp[s]) - m);
    red[tid] = sum; __syncthreads();
    for (int off = 128; off > 0; off >>= 1) {
        if (tid < off) red[tid] += red[tid + off];
        __syncthreads();
    }
    float inv = 1.0f / red[0];
    for (int s = tid; s < S; s += 256) {
        float v = sp[s];
        out[((size_t)b * S + s) * (D + 1)] = signf(v) * expf(fabsf(v) - m) * inv;
    }
}

// ---------- q / kT projections ----------
__global__ void __launch_bounds__(256) k_qk(const float* __restrict__ val1,
                                            const float* __restrict__ pair_a,
                                            const float* __restrict__ pair_b,
                                            float* __restrict__ q,
                                            float* __restrict__ kkT) {
    __shared__ __align__(16) float vrow[NR][D];   // 32 KB
    __shared__ float redq[256];
    __shared__ float redk[256];
    int tid = threadIdx.x;
    int blk = ((blockIdx.x & 7) << 7) | (blockIdx.x >> 3);  // XCD k <-> b=k
    int rowbase = blk * NR;           // = b*S + sbase (never straddles b)
    int b = rowbase >> 11;
    int sbase = rowbase & (S - 1);
    {
        const float4* gv = (const float4*)(val1 + (size_t)rowbase * D);
        float4* lv = (float4*)&vrow[0][0];
        for (int i = tid; i < NR * D / 4; i += 256) lv[i] = gv[i];
    }
    __syncthreads();
    int r = tid & 63, grp = tid >> 6;
    float accq[NR], acck[NR];
#pragma unroll
    for (int rr = 0; rr < NR; rr++) { accq[rr] = 0.f; acck[rr] = 0.f; }
    for (int d0 = grp * 128; d0 < grp * 128 + 128; d0 += 4) {
#pragma unroll
        for (int dd = 0; dd < 4; dd++) {
            float a  = pair_a[(size_t)(d0 + dd) * R + r];
            float bb = pair_b[(size_t)(d0 + dd) * R + r];
#pragma unroll
            for (int rr = 0; rr < NR; rr++) {
                float v = vrow[rr][d0 + dd];
                accq[rr] += v * a;
                acck[rr] += v * bb;
            }
        }
    }
    for (int rr = 0; rr < NR; rr++) {
        redq[tid] = accq[rr]; redk[tid] = acck[rr];
        __syncthreads();
        if (tid < 64) {
            float qv = redq[tid] + redq[tid + 64] + redq[tid + 128] + redq[tid + 192];
            float kv = redk[tid] + redk[tid + 64] + redk[tid + 128] + redk[tid + 192];
            q[(size_t)(rowbase + rr) * R + tid] = qv;
            kkT[((size_t)b * R + tid) * S + (sbase + rr)] = kv;
        }
        __syncthreads();
    }
}

// ---------- pscore: p = q.kT (float4), per-wave topk -> eidx/ew ----------
// 512 threads, NI=8: each block reads the 512 KB kkT slab once for 8 rows,
// halving per-XCD L2 traffic vs NI=4.
__global__ void __launch_bounds__(512) k_pscore(const float* __restrict__ q,
                                                const float* __restrict__ kkT,
                                                int* __restrict__ eidx,
                                                float* __restrict__ ew_g) {
    __shared__ __align__(16) float prow[NI][S];   // 64 KB
    __shared__ __align__(16) float qrow[NI][R];   // 2 KB
    __shared__ unsigned long long cand[NI][64];   // 4 KB

    int tid = threadIdx.x;
    int lane = tid & 63, wv = tid >> 6;
    int blk = ((blockIdx.x & 7) << 8) | (blockIdx.x >> 3);  // 2048 blocks, XCD k <-> b=k
    int ibase = blk * NI;            // global row base (never straddles b)
    int b = ibase >> 11;             // S = 2048

    {
        int rr = tid >> 6, r = tid & 63;
        qrow[rr][r] = q[(size_t)(ibase + rr) * R + r];
    }
    __syncthreads();

    // p rows (float4 over j; kkT slice reused by 8 rows)
    {
        const float4* kk4 = (const float4*)(kkT + (size_t)b * R * S);
        int j4 = tid;                // 512 threads cover S/4 = 512
        float4 acc[NI];
#pragma unroll
        for (int rr = 0; rr < NI; rr++) acc[rr] = make_float4(0.f, 0.f, 0.f, 0.f);
        for (int r0 = 0; r0 < R; r0 += 4) {
            float4 qv[NI];
#pragma unroll
            for (int rr = 0; rr < NI; rr++) qv[rr] = *(const float4*)&qrow[rr][r0];
#define P_STEP(dr, comp)                                                       \
            {                                                                  \
                float4 kv = kk4[(size_t)(r0 + dr) * (S / 4) + j4];             \
                _Pragma("unroll")                                              \
                for (int rr = 0; rr < NI; rr++) {                              \
                    float c = qv[rr].comp;                                     \
                    acc[rr].x += c * kv.x; acc[rr].y += c * kv.y;              \
                    acc[rr].z += c * kv.z; acc[rr].w += c * kv.w;              \
                }                                                              \
            }
            P_STEP(0, x) P_STEP(1, y) P_STEP(2, z) P_STEP(3, w)
#undef P_STEP
        }
#pragma unroll
        for (int rr = 0; rr < NI; rr++)
            ((float4*)&prow[rr][0])[j4] = acc[rr];
    }
    __syncthreads();

    // ---- per-wave topk on row ibase + wv (8 waves, 8 rows) ----
    int row = ibase + wv;
    float myg; int myj;
    topk16_row(&prow[wv][0], &cand[wv][0], lane, myg, myj);

    float m = __shfl(fabsf(myg), 0);
    float e = (lane < KTOP) ? expf(fabsf(myg) - m) : 0.f;
    float esum = e;
#pragma unroll
    for (int off = 8; off > 0; off >>= 1) esum += __shfl_xor(esum, off, 64);
    esum = __shfl(esum, 0);
    float myw = signf(myg) * e / esum;

    if (lane < KTOP) {
        eidx[(size_t)row * KTOP + lane] = myj;
        ew_g[(size_t)row * KTOP + lane] = myw;
    }
}

// ---------- mix: gather neighbors, residual add, unit-norm, out[...,1:] ----------
__global__ void __launch_bounds__(256) k_mix(const int* __restrict__ eidx,
                                             const float* __restrict__ ew_g,
                                             const float* __restrict__ val1,
                                             float* __restrict__ out) {
    int lane = threadIdx.x & 63, wv = threadIdx.x >> 6;
    int blk = ((blockIdx.x & 7) << 9) | (blockIdx.x >> 3);  // XCD k <-> b=k
    int row = blk * 4 + wv;
    int b = row >> 11;

    int e_i = 0; float e_w = 0.f;
    if (lane < KTOP) {
        e_i = eidx[(size_t)row * KTOP + lane];
        e_w = ew_g[(size_t)row * KTOP + lane];
    }

    const float4* self4 = (const float4*)(val1 + (size_t)row * D);
    float4 a0 = self4[lane], a1 = self4[lane + 64];
#pragma unroll
    for (int k = 0; k < KTOP; k++) {
        int j = __shfl(e_i, k);
        float w = __shfl(e_w, k);
        const float4* nb4 = (const float4*)(val1 + ((size_t)b * S + j) * D);
        float4 v0 = nb4[lane], v1 = nb4[lane + 64];
        a0.x += w * v0.x; a0.y += w * v0.y; a0.z += w * v0.z; a0.w += w * v0.w;
        a1.x += w * v1.x; a1.y += w * v1.y; a1.z += w * v1.z; a1.w += w * v1.w;
    }
    float ss = a0.x * a0.x + a0.y * a0.y + a0.z * a0.z + a0.w * a0.w
             + a1.x * a1.x + a1.y * a1.y + a1.z * a1.z + a1.w * a1.w;
#pragma unroll
    for (int off = 32; off > 0; off >>= 1) ss += __shfl_xor(ss, off, 64);
    float sc = 1.0f / (sqrtf(ss) + 1e-6f);
    float* op = out + (size_t)row * (D + 1) + 1;
    int d0 = 4 * lane;
    op[d0 + 0] = a0.x * sc; op[d0 + 1] = a0.y * sc;
    op[d0 + 2] = a0.z * sc; op[d0 + 3] = a0.w * sc;
    op[256 + d0 + 0] = a1.x * sc; op[256 + d0 + 1] = a1.y * sc;
    op[256 + d0 + 2] = a1.z * sc; op[256 + d0 + 3] = a1.w * sc;
}

extern "C" void kernel_launch(void* const* d_in, const int* in_sizes, int n_in,
                              void* d_out, int out_size, void* d_ws, size_t ws_size,
                              hipStream_t stream) {
    (void)in_sizes; (void)n_in; (void)out_size; (void)ws_size;
    const float* x          = (const float*)d_in[0];
    const float* init_state = (const float*)d_in[1];
    const float* init_val   = (const float*)d_in[2];
    const float* route_a    = (const float*)d_in[3];
    const float* route_b    = (const float*)d_in[4];
    const float* pair_a     = (const float*)d_in[5];
    const float* pair_b     = (const float*)d_in[6];
    float* out = (float*)d_out;

    float* ws       = (float*)d_ws;
    float* val1     = ws;                             // B*S*D
    float* q        = val1 + (size_t)B * S * D;       // B*S*R
    float* kkT      = q    + (size_t)B * S * R;       // B*R*S
    float* state_ws = kkT  + (size_t)B * R * S;       // B*S
    float* coef     = state_ws + (size_t)B * S;       // B*T*K
    int*   bincount = (int*)(coef + (size_t)B * T * KTOP);   // B*S
    int*   binlist  = bincount + (size_t)B * S;              // B*S*CAP
    // eidx/ew reuse binlist space (binlist dead after k_accum)
    int*   eidx     = binlist;                               // B*S*K
    float* ew       = (float*)(binlist + (size_t)B * S * KTOP);  // B*S*K

    hipMemsetAsync(bincount, 0, (size_t)B * S * sizeof(int), stream);
    hipLaunchKernelGGL(k_init_state, dim3(B), dim3(256), 0, stream, init_state, state_ws);
    hipLaunchKernelGGL(k_bcast, dim3(B * S / 4), dim3(256), 0, stream, init_val, val1);
    hipLaunchKernelGGL(k_score, dim3(B * T / NT), dim3(256), 0, stream,
                       x, route_a, route_b, val1, state_ws, coef, bincount, binlist);
    hipLaunchKernelGGL(k_state_final, dim3(B), dim3(256), 0, stream, state_ws, out);
    hipLaunchKernelGGL(k_accum, dim3(B * S / 4), dim3(256), 0, stream,
                       x, coef, bincount, binlist, val1);
    hipLaunchKernelGGL(k_qk, dim3(B * S / NR), dim3(256), 0, stream,
                       val1, pair_a, pair_b, q, kkT);
    hipLaunchKernelGGL(k_pscore, dim3(B * S / NI), dim3(512), 0, stream,
                       q, kkT, eidx, ew);
    hipLaunchKernelGGL(k_mix, dim3(B * S / 4), dim3(256), 0, stream,
                       eidx, ew, val1, out);
}

// Round 3
// 413.099 us; speedup vs baseline: 1.2579x; 1.0487x over previous
//
#include <hip/hip_runtime.h>
#include <cmath>

namespace {
constexpr int B = 8;
constexpr int T = 2048;
constexpr int D = 512;
constexpr int S = 2048;
constexpr int R = 64;
constexpr int KTOP = 16;
constexpr int NT = 8;    // tokens per block in score kernel (512 threads)
constexpr int NR = 16;   // rows per block in qk kernel
constexpr int NI = 8;    // rows per block in pscore kernel (512 threads)
constexpr int CAP = 256; // bin capacity per (b,slot); overflow -> atomic fallback

__device__ __forceinline__ float signf(float v) {
    return (v > 0.f) ? 1.f : ((v < 0.f) ? -1.f : 0.f);
}

// Exact top-16 by |value| (ties -> lower index) over a wave-private LDS row of S
// floats. Result: lane k (k<16) gets myg = signed value, myj = index, in exact
// descending (|v|, -j) order. Row contents are preserved on the fast path.
__device__ __forceinline__ void topk16_row(float* __restrict__ row,
                                           unsigned long long* __restrict__ cand,
                                           int lane, float& myg, int& myj) {
    const float4* p4 = (const float4*)row;
    // Phase 1: per-lane abs max over 32 elements
    float lmax = 0.f;
#pragma unroll
    for (int i = 0; i < 8; i++) {
        float4 v = p4[lane + 64 * i];
        lmax = fmaxf(lmax, fmaxf(fmaxf(fabsf(v.x), fabsf(v.y)),
                                 fmaxf(fabsf(v.z), fabsf(v.w))));
    }
    // Phase 2: bitonic sort (descending) of 64 lane maxes; t = 16th largest
    {
        float v = lmax;
#pragma unroll
        for (int size = 2; size <= 64; size <<= 1) {
#pragma unroll
            for (int stride = size >> 1; stride > 0; stride >>= 1) {
                float o = __shfl_xor(v, stride, 64);
                bool takeMax = ((lane & size) == 0) == ((lane & stride) == 0);
                v = takeMax ? fmaxf(v, o) : fminf(v, o);
            }
        }
        lmax = __shfl(v, 15);
    }
    float t = lmax;
    // Phase 3: count candidates with |v| >= t, prefix-sum, compact into cand[]
    int cnt = 0;
#pragma unroll
    for (int i = 0; i < 8; i++) {
        float4 v = p4[lane + 64 * i];
        cnt += (fabsf(v.x) >= t) + (fabsf(v.y) >= t) +
               (fabsf(v.z) >= t) + (fabsf(v.w) >= t);
    }
    int off = cnt;
#pragma unroll
    for (int d = 1; d < 64; d <<= 1) {
        int o = __shfl_up(off, d, 64);
        if (lane >= d) off += o;
    }
    int total = __shfl(off, 63);
    int base = off - cnt;

    if (total <= 64) {
        int pos = base;
#pragma unroll
        for (int i = 0; i < 8; i++) {
            float4 v = p4[lane + 64 * i];
            int jb = 4 * (lane + 64 * i);
            float c[4] = {v.x, v.y, v.z, v.w};
#pragma unroll
            for (int cc = 0; cc < 4; cc++) {
                if (fabsf(c[cc]) >= t) {
                    unsigned ab = __float_as_uint(c[cc]) & 0x7fffffffu;
                    cand[pos++] = ((unsigned long long)ab << 11) |
                                  (unsigned)(2047 - (jb + cc));
                }
            }
        }
        // Phase 4: bitonic sort (descending) of up to 64 u64 keys
        unsigned long long key = (lane < total) ? cand[lane] : 0ull;
#pragma unroll
        for (int size = 2; size <= 64; size <<= 1) {
#pragma unroll
            for (int stride = size >> 1; stride > 0; stride >>= 1) {
                unsigned long long o = __shfl_xor((long long)key, stride, 64);
                bool takeMax = ((lane & size) == 0) == ((lane & stride) == 0);
                key = (takeMax == (key > o)) ? key : o;
            }
        }
        myg = 0.f; myj = 0;
        if (lane < KTOP) {
            myj = 2047 - (int)(key & 2047ull);
            myg = row[myj];
        }
    } else {
        // Fallback (rare): 16 rounds of full-row argmax with removal
        myg = 0.f; myj = 0;
        for (int k = 0; k < KTOP; k++) {
            float bv = -1.f, bs = 0.f; int bj = 0;
#pragma unroll
            for (int i = 0; i < 8; i++) {
                float4 v = p4[lane + 64 * i];
                int jb = 4 * (lane + 64 * i);
                { float a = fabsf(v.x); if (a > bv) { bv = a; bs = v.x; bj = jb; } }
                { float a = fabsf(v.y); if (a > bv) { bv = a; bs = v.y; bj = jb + 1; } }
                { float a = fabsf(v.z); if (a > bv) { bv = a; bs = v.z; bj = jb + 2; } }
                { float a = fabsf(v.w); if (a > bv) { bv = a; bs = v.w; bj = jb + 3; } }
            }
#pragma unroll
            for (int off2 = 32; off2 > 0; off2 >>= 1) {
                float ov = __shfl_xor(bv, off2, 64);
                float os = __shfl_xor(bs, off2, 64);
                int   oj = __shfl_xor(bj, off2, 64);
                if (ov > bv || (ov == bv && oj < bj)) { bv = ov; bs = os; bj = oj; }
            }
            if (lane == k) { myg = bs; myj = bj; }
            if (lane == 0) row[bj] = 0.f;
        }
    }
}
} // namespace

// ---------- state init: state_ws[b][s] = sign * softmax(|init_state|) ----------
__global__ void k_init_state(const float* __restrict__ init_state,
                             float* __restrict__ state_ws) {
    int b = blockIdx.x;
    int tid = threadIdx.x;
    __shared__ float red[256];
    float m = -1e30f;
    for (int s = tid; s < S; s += 256) m = fmaxf(m, fabsf(init_state[s]));
    red[tid] = m; __syncthreads();
    for (int off = 128; off > 0; off >>= 1) {
        if (tid < off) red[tid] = fmaxf(red[tid], red[tid + off]);
        __syncthreads();
    }
    m = red[0]; __syncthreads();
    float sum = 0.f;
    for (int s = tid; s < S; s += 256) sum += expf(fabsf(init_state[s]) - m);
    red[tid] = sum; __syncthreads();
    for (int off = 128; off > 0; off >>= 1) {
        if (tid < off) red[tid] += red[tid + off];
        __syncthreads();
    }
    float inv = 1.0f / red[0];
    for (int s = tid; s < S; s += 256) {
        float v = init_state[s];
        state_ws[(size_t)b * S + s] = signf(v) * expf(fabsf(v) - m) * inv;
    }
}

// ---------- val broadcast init: val1[b][s][:] = unit_norm(init_val[s]) ----------
__global__ void k_bcast(const float* __restrict__ init_val,
                        float* __restrict__ val1) {
    int wv = threadIdx.x >> 6;
    int lane = threadIdx.x & 63;
    int blk = ((blockIdx.x & 7) << 9) | (blockIdx.x >> 3);  // XCD k <-> b=k
    int row = blk * 4 + wv;               // row = b*S + s
    int s = row & (S - 1);
    const float4* src = (const float4*)(init_val + (size_t)s * D);
    float4 v0 = src[lane], v1 = src[lane + 64];
    float ss = v0.x * v0.x + v0.y * v0.y + v0.z * v0.z + v0.w * v0.w
             + v1.x * v1.x + v1.y * v1.y + v1.z * v1.z + v1.w * v1.w;
#pragma unroll
    for (int off = 32; off > 0; off >>= 1) ss += __shfl_xor(ss, off, 64);
    float sc = 1.0f / (sqrtf(ss) + 1e-6f);
    v0.x *= sc; v0.y *= sc; v0.z *= sc; v0.w *= sc;
    v1.x *= sc; v1.y *= sc; v1.z *= sc; v1.w *= sc;
    float4* dst = (float4*)(val1 + (size_t)row * D);
    dst[lane] = v0; dst[lane + 64] = v1;
}

// ---------- score stage: route scores -> per-wave topk -> bin lists ----------
// NT=8 @ 512 threads: halves per-block route_a/route_b L2 traffic vs NT=4.
// LDS 70 KB -> 2 blocks/CU = 16 waves/CU. xs (16 KB) and red4 (16 KB) are
// overlaid inside sc (64 KB); live ranges separated by barriers.
__global__ void __launch_bounds__(512, 4) k_score(const float* __restrict__ x,
                                                  const float* __restrict__ route_a,
                                                  const float* __restrict__ route_b,
                                                  float* __restrict__ val1,
                                                  float* __restrict__ state_ws,
                                                  float* __restrict__ coef,
                                                  int* __restrict__ bincount,
                                                  int* __restrict__ binlist) {
    __shared__ __align__(16) char smem[NT * S * 4]; // 64 KB: xs -> red4 -> sc
    __shared__ __align__(16) float xr[NT][R];       // 2 KB
    __shared__ unsigned long long cand[NT][64];     // 4 KB
    float (*sc)[S] = (float(*)[S])smem;
    float (*xs)[D] = (float(*)[D])smem;             // overlay (x-load + acc read)
    float (*red4)[512] = (float(*)[512])smem;       // overlay (reduction only)

    int tid = threadIdx.x;
    int lane = tid & 63, wv = tid >> 6;
    int blk = ((blockIdx.x & 7) << 8) | (blockIdx.x >> 3);  // XCD k <-> b=k
    int tb = blk * NT;              // global token base (block never straddles b)
    int b = tb >> 11;               // T = 2048
    int t0 = tb & (T - 1);

    // load 8 x rows into LDS (1024 float4, 512 threads)
    {
        const float4* xg = (const float4*)(x + (size_t)tb * D);
        float4* xls = (float4*)smem;
        xls[tid] = xg[tid];
        xls[tid + 512] = xg[tid + 512];
    }
    __syncthreads();

    // xr = x . route_a  (wave wv covers d in [wv*64, wv*64+64), r = lane)
    {
        int r = lane;
        float acc[NT];
#pragma unroll
        for (int tt = 0; tt < NT; tt++) acc[tt] = 0.f;
        for (int d0 = wv * 64; d0 < wv * 64 + 64; d0 += 4) {
            float a0 = route_a[(size_t)(d0 + 0) * R + r];
            float a1 = route_a[(size_t)(d0 + 1) * R + r];
            float a2 = route_a[(size_t)(d0 + 2) * R + r];
            float a3 = route_a[(size_t)(d0 + 3) * R + r];
#pragma unroll
            for (int tt = 0; tt < NT; tt++) {
                float4 xv = *(const float4*)&xs[tt][d0];
                acc[tt] += xv.x * a0 + xv.y * a1 + xv.z * a2 + xv.w * a3;
            }
        }
        __syncthreads();   // xs dead; red4 region writable
#pragma unroll
        for (int tt = 0; tt < NT; tt++) red4[tt][tid] = acc[tt];
        __syncthreads();
        {
            int tt2 = tid >> 6, r2 = tid & 63;
            float s = 0.f;
#pragma unroll
            for (int g = 0; g < 8; g++) s += red4[tt2][g * 64 + r2];
            xr[tt2][r2] = s;
        }
        __syncthreads();   // red4 dead; sc writable
    }

    // scores = xr . route_b  (float4 over s; 512 threads cover S/4 = 512)
    {
        const float4* rb4 = (const float4*)route_b;
        int j4 = tid;
        float4 acc[NT];
#pragma unroll
        for (int tt = 0; tt < NT; tt++) acc[tt] = make_float4(0.f, 0.f, 0.f, 0.f);
        for (int r0 = 0; r0 < R; r0 += 4) {
            float4 xv[NT];
#pragma unroll
            for (int tt = 0; tt < NT; tt++) xv[tt] = *(const float4*)&xr[tt][r0];
#define SCORE_STEP(dr, comp)                                                   \
            {                                                                  \
                float4 bv = rb4[(size_t)(r0 + dr) * (S / 4) + j4];             \
                _Pragma("unroll")                                              \
                for (int tt = 0; tt < NT; tt++) {                              \
                    float c = xv[tt].comp;                                     \
                    acc[tt].x += c * bv.x; acc[tt].y += c * bv.y;              \
                    acc[tt].z += c * bv.z; acc[tt].w += c * bv.w;              \
                }                                                              \
            }
            SCORE_STEP(0, x) SCORE_STEP(1, y) SCORE_STEP(2, z) SCORE_STEP(3, w)
#undef SCORE_STEP
        }
#pragma unroll
        for (int tt = 0; tt < NT; tt++)
            ((float4*)&sc[tt][0])[j4] = acc[tt];
    }
    __syncthreads();

    // ---- per-wave from here: wave wv owns token tt = wv ----
    int tt = wv;
    int tloc = t0 + tt;
    int tglob = tb + tt;

    // x inverse norm (coalesced global re-read; row is L2-hot)
    float xinv;
    {
        const float4* xg = (const float4*)(x + (size_t)tglob * D);
        float4 x0 = xg[lane], x1 = xg[lane + 64];
        float ss = x0.x * x0.x + x0.y * x0.y + x0.z * x0.z + x0.w * x0.w
                 + x1.x * x1.x + x1.y * x1.y + x1.z * x1.z + x1.w * x1.w;
#pragma unroll
        for (int off = 32; off > 0; off >>= 1) ss += __shfl_xor(ss, off, 64);
        xinv = 1.0f / (sqrtf(ss) + 1e-6f);
    }

    float myg; int myj;
    topk16_row(&sc[tt][0], &cand[wv][0], lane, myg, myj);

    // signed-abs-softmax over the 16 winners (lane k holds winner k)
    float m = __shfl(fabsf(myg), 0);
    float e = (lane < KTOP) ? expf(fabsf(myg) - m) : 0.f;
    float esum = e;
#pragma unroll
    for (int off = 8; off > 0; off >>= 1) esum += __shfl_xor(esum, off, 64);
    esum = __shfl(esum, 0);
    float w = signf(myg) * e / esum;
    float coefv = w * xinv;

    unsigned long long ovf = 0ull;
    int pos = 0;
    if (lane < KTOP) {
        float sp = (myg > 20.f) ? myg : log1pf(expf(myg));
        atomicAdd(&state_ws[(size_t)b * S + myj], sp);
        pos = atomicAdd(&bincount[(size_t)b * S + myj], 1);
        if (pos < CAP) {
            binlist[((size_t)b * S + myj) * CAP + pos] = (tloc << 4) | lane;
            coef[(size_t)tglob * KTOP + lane] = coefv;
        }
    }
    ovf = __ballot(lane < KTOP && pos >= CAP);
    while (ovf) {   // overflow fallback (essentially never)
        int src = __ffsll(ovf) - 1;
        int j = __shfl(myj, src);
        float c = __shfl(coefv, src);
        float* dst = val1 + ((size_t)b * S + j) * D;
        const float* xrow = x + (size_t)tglob * D;
#pragma unroll
        for (int i = 0; i < 8; i++)
            atomicAdd(&dst[lane + 64 * i], c * xrow[lane + 64 * i]);
        ovf &= ovf - 1;
    }
}

// ---------- accumulate bins: val1[row] = unit_norm(val1[row] + sum c*x) ----------
__global__ void __launch_bounds__(256) k_accum(const float* __restrict__ x,
                                               const float* __restrict__ coef,
                                               const int* __restrict__ bincount,
                                               const int* __restrict__ binlist,
                                               float* __restrict__ val1) {
    int lane = threadIdx.x & 63, wv = threadIdx.x >> 6;
    int blk = ((blockIdx.x & 7) << 9) | (blockIdx.x >> 3);  // XCD k <-> b=k
    int row = blk * 4 + wv;             // row = b*S + s
    int b = row >> 11;                  // S = 2048
    float4* vp4 = (float4*)(val1 + (size_t)row * D);
    float4 a0 = vp4[lane], a1 = vp4[lane + 64];
    int n = bincount[row]; if (n > CAP) n = CAP;
    const int* lp = binlist + (size_t)row * CAP;
    for (int base = 0; base < n; base += 64) {
        int mm = n - base; if (mm > 64) mm = 64;
        int ent = 0; float cc = 0.f;
        if (lane < mm) {
            ent = lp[base + lane];
            cc = coef[((size_t)b * T + (ent >> 4)) * KTOP + (ent & 15)];
        }
        // 1-deep software pipeline over the gather loop
        int e0 = __shfl(ent, 0);
        const float4* xp4 = (const float4*)(x + ((size_t)b * T + (e0 >> 4)) * D);
        float4 v0 = xp4[lane], v1 = xp4[lane + 64];
        for (int k = 0; k < mm; k++) {
            float c = __shfl(cc, k);
            float4 c0 = v0, c1 = v1;
            if (k + 1 < mm) {
                int e2 = __shfl(ent, k + 1);
                const float4* np4 = (const float4*)(x + ((size_t)b * T + (e2 >> 4)) * D);
                v0 = np4[lane]; v1 = np4[lane + 64];
            }
            a0.x += c * c0.x; a0.y += c * c0.y; a0.z += c * c0.z; a0.w += c * c0.w;
            a1.x += c * c1.x; a1.y += c * c1.y; a1.z += c * c1.z; a1.w += c * c1.w;
        }
    }
    float ss = a0.x * a0.x + a0.y * a0.y + a0.z * a0.z + a0.w * a0.w
             + a1.x * a1.x + a1.y * a1.y + a1.z * a1.z + a1.w * a1.w;
#pragma unroll
    for (int off = 32; off > 0; off >>= 1) ss += __shfl_xor(ss, off, 64);
    float sc = 1.0f / (sqrtf(ss) + 1e-6f);
    a0.x *= sc; a0.y *= sc; a0.z *= sc; a0.w *= sc;
    a1.x *= sc; a1.y *= sc; a1.z *= sc; a1.w *= sc;
    vp4[lane] = a0; vp4[lane + 64] = a1;
}

// ---------- state finalize: signed-abs-softmax -> out[...,0] ----------
__global__ void k_state_final(const float* __restrict__ state_ws,
                              float* __restrict__ out) {
    int b = blockIdx.x;
    int tid = threadIdx.x;
    __shared__ float red[256];
    const float* sp = state_ws + (size_t)b * S;
    float m = -1e30f;
    for (int s = tid; s < S; s += 256) m = fmaxf(m, fabsf(sp[s]));
    red[tid] = m; __syncthreads();
    for (int off = 128; off > 0; off >>= 1) {
        if (tid < off) red[tid] = fmaxf(red[tid], red[tid + off]);
        __syncthreads();
    }
    m = red[0]; __syncthreads();
    float sum = 0.f;
    for (int s = tid; s < S; s += 256) sum += expf(fabsf(sp[s]) - m);
    red[tid] = sum; __syncthreads();
    for (int off = 128; off > 0; off >>= 1) {
        if (tid < off) red[tid] += red[tid + off];
        __syncthreads();
    }
    float inv = 1.0f / red[0];
    for (int s = tid; s < S; s += 256) {
        float v = sp[s];
        out[((size_t)b * S + s) * (D + 1)] = signf(v) * expf(fabsf(v) - m) * inv;
    }
}

// ---------- q / kT projections ----------
__global__ void __launch_bounds__(256) k_qk(const float* __restrict__ val1,
                                            const float* __restrict__ pair_a,
                                            const float* __restrict__ pair_b,
                                            float* __restrict__ q,
                                            float* __restrict__ kkT) {
    __shared__ __align__(16) float vrow[NR][D];   // 32 KB
    __shared__ float redq[256];
    __shared__ float redk[256];
    int tid = threadIdx.x;
    int blk = ((blockIdx.x & 7) << 7) | (blockIdx.x >> 3);  // XCD k <-> b=k
    int rowbase = blk * NR;           // = b*S + sbase (never straddles b)
    int b = rowbase >> 11;
    int sbase = rowbase & (S - 1);
    {
        const float4* gv = (const float4*)(val1 + (size_t)rowbase * D);
        float4* lv = (float4*)&vrow[0][0];
        for (int i = tid; i < NR * D / 4; i += 256) lv[i] = gv[i];
    }
    __syncthreads();
    int r = tid & 63, grp = tid >> 6;
    float accq[NR], acck[NR];
#pragma unroll
    for (int rr = 0; rr < NR; rr++) { accq[rr] = 0.f; acck[rr] = 0.f; }
    for (int d0 = grp * 128; d0 < grp * 128 + 128; d0 += 4) {
#pragma unroll
        for (int dd = 0; dd < 4; dd++) {
            float a  = pair_a[(size_t)(d0 + dd) * R + r];
            float bb = pair_b[(size_t)(d0 + dd) * R + r];
#pragma unroll
            for (int rr = 0; rr < NR; rr++) {
                float v = vrow[rr][d0 + dd];
                accq[rr] += v * a;
                acck[rr] += v * bb;
            }
        }
    }
    for (int rr = 0; rr < NR; rr++) {
        redq[tid] = accq[rr]; redk[tid] = acck[rr];
        __syncthreads();
        if (tid < 64) {
            float qv = redq[tid] + redq[tid + 64] + redq[tid + 128] + redq[tid + 192];
            float kv = redk[tid] + redk[tid + 64] + redk[tid + 128] + redk[tid + 192];
            q[(size_t)(rowbase + rr) * R + tid] = qv;
            kkT[((size_t)b * R + tid) * S + (sbase + rr)] = kv;
        }
        __syncthreads();
    }
}

// ---------- pscore: p = q.kT (float4), per-wave topk -> eidx/ew ----------
__global__ void __launch_bounds__(512) k_pscore(const float* __restrict__ q,
                                                const float* __restrict__ kkT,
                                                int* __restrict__ eidx,
                                                float* __restrict__ ew_g) {
    __shared__ __align__(16) float prow[NI][S];   // 64 KB
    __shared__ __align__(16) float qrow[NI][R];   // 2 KB
    __shared__ unsigned long long cand[NI][64];   // 4 KB

    int tid = threadIdx.x;
    int lane = tid & 63, wv = tid >> 6;
    int blk = ((blockIdx.x & 7) << 8) | (blockIdx.x >> 3);  // XCD k <-> b=k
    int ibase = blk * NI;            // global row base (never straddles b)
    int b = ibase >> 11;             // S = 2048

    {
        int rr = tid >> 6, r = tid & 63;
        qrow[rr][r] = q[(size_t)(ibase + rr) * R + r];
    }
    __syncthreads();

    // p rows (float4 over j; kkT slice reused by 8 rows)
    {
        const float4* kk4 = (const float4*)(kkT + (size_t)b * R * S);
        int j4 = tid;                // 512 threads cover S/4 = 512
        float4 acc[NI];
#pragma unroll
        for (int rr = 0; rr < NI; rr++) acc[rr] = make_float4(0.f, 0.f, 0.f, 0.f);
        for (int r0 = 0; r0 < R; r0 += 4) {
            float4 qv[NI];
#pragma unroll
            for (int rr = 0; rr < NI; rr++) qv[rr] = *(const float4*)&qrow[rr][r0];
#define P_STEP(dr, comp)                                                       \
            {                                                                  \
                float4 kv = kk4[(size_t)(r0 + dr) * (S / 4) + j4];             \
                _Pragma("unroll")                                              \
                for (int rr = 0; rr < NI; rr++) {                              \
                    float c = qv[rr].comp;                                     \
                    acc[rr].x += c * kv.x; acc[rr].y += c * kv.y;              \
                    acc[rr].z += c * kv.z; acc[rr].w += c * kv.w;              \
                }                                                              \
            }
            P_STEP(0, x) P_STEP(1, y) P_STEP(2, z) P_STEP(3, w)
#undef P_STEP
        }
#pragma unroll
        for (int rr = 0; rr < NI; rr++)
            ((float4*)&prow[rr][0])[j4] = acc[rr];
    }
    __syncthreads();

    // ---- per-wave topk on row ibase + wv (8 waves, 8 rows) ----
    int row = ibase + wv;
    float myg; int myj;
    topk16_row(&prow[wv][0], &cand[wv][0], lane, myg, myj);

    float m = __shfl(fabsf(myg), 0);
    float e = (lane < KTOP) ? expf(fabsf(myg) - m) : 0.f;
    float esum = e;
#pragma unroll
    for (int off = 8; off > 0; off >>= 1) esum += __shfl_xor(esum, off, 64);
    esum = __shfl(esum, 0);
    float myw = signf(myg) * e / esum;

    if (lane < KTOP) {
        eidx[(size_t)row * KTOP + lane] = myj;
        ew_g[(size_t)row * KTOP + lane] = myw;
    }
}

// ---------- mix: gather neighbors, residual add, unit-norm, out[...,1:] ----------
__global__ void __launch_bounds__(256) k_mix(const int* __restrict__ eidx,
                                             const float* __restrict__ ew_g,
                                             const float* __restrict__ val1,
                                             float* __restrict__ out) {
    int lane = threadIdx.x & 63, wv = threadIdx.x >> 6;
    int blk = ((blockIdx.x & 7) << 9) | (blockIdx.x >> 3);  // XCD k <-> b=k
    int row = blk * 4 + wv;
    int b = row >> 11;

    int e_i = 0; float e_w = 0.f;
    if (lane < KTOP) {
        e_i = eidx[(size_t)row * KTOP + lane];
        e_w = ew_g[(size_t)row * KTOP + lane];
    }

    const float4* self4 = (const float4*)(val1 + (size_t)row * D);
    float4 a0 = self4[lane], a1 = self4[lane + 64];
#pragma unroll
    for (int k = 0; k < KTOP; k++) {
        int j = __shfl(e_i, k);
        float w = __shfl(e_w, k);
        const float4* nb4 = (const float4*)(val1 + ((size_t)b * S + j) * D);
        float4 v0 = nb4[lane], v1 = nb4[lane + 64];
        a0.x += w * v0.x; a0.y += w * v0.y; a0.z += w * v0.z; a0.w += w * v0.w;
        a1.x += w * v1.x; a1.y += w * v1.y; a1.z += w * v1.z; a1.w += w * v1.w;
    }
    float ss = a0.x * a0.x + a0.y * a0.y + a0.z * a0.z + a0.w * a0.w
             + a1.x * a1.x + a1.y * a1.y + a1.z * a1.z + a1.w * a1.w;
#pragma unroll
    for (int off = 32; off > 0; off >>= 1) ss += __shfl_xor(ss, off, 64);
    float sc = 1.0f / (sqrtf(ss) + 1e-6f);
    float* op = out + (size_t)row * (D + 1) + 1;
    int d0 = 4 * lane;
    op[d0 + 0] = a0.x * sc; op[d0 + 1] = a0.y * sc;
    op[d0 + 2] = a0.z * sc; op[d0 + 3] = a0.w * sc;
    op[256 + d0 + 0] = a1.x * sc; op[256 + d0 + 1] = a1.y * sc;
    op[256 + d0 + 2] = a1.z * sc; op[256 + d0 + 3] = a1.w * sc;
}

extern "C" void kernel_launch(void* const* d_in, const int* in_sizes, int n_in,
                              void* d_out, int out_size, void* d_ws, size_t ws_size,
                              hipStream_t stream) {
    (void)in_sizes; (void)n_in; (void)out_size; (void)ws_size;
    const float* x          = (const float*)d_in[0];
    const float* init_state = (const float*)d_in[1];
    const float* init_val   = (const float*)d_in[2];
    const float* route_a    = (const float*)d_in[3];
    const float* route_b    = (const float*)d_in[4];
    const float* pair_a     = (const float*)d_in[5];
    const float* pair_b     = (const float*)d_in[6];
    float* out = (float*)d_out;

    float* ws       = (float*)d_ws;
    float* val1     = ws;                             // B*S*D
    float* q        = val1 + (size_t)B * S * D;       // B*S*R
    float* kkT      = q    + (size_t)B * S * R;       // B*R*S
    float* state_ws = kkT  + (size_t)B * R * S;       // B*S
    float* coef     = state_ws + (size_t)B * S;       // B*T*K
    int*   bincount = (int*)(coef + (size_t)B * T * KTOP);   // B*S
    int*   binlist  = bincount + (size_t)B * S;              // B*S*CAP
    // eidx/ew reuse binlist space (binlist dead after k_accum)
    int*   eidx     = binlist;                               // B*S*K
    float* ew       = (float*)(binlist + (size_t)B * S * KTOP);  // B*S*K

    hipMemsetAsync(bincount, 0, (size_t)B * S * sizeof(int), stream);
    hipLaunchKernelGGL(k_init_state, dim3(B), dim3(256), 0, stream, init_state, state_ws);
    hipLaunchKernelGGL(k_bcast, dim3(B * S / 4), dim3(256), 0, stream, init_val, val1);
    hipLaunchKernelGGL(k_score, dim3(B * T / NT), dim3(512), 0, stream,
                       x, route_a, route_b, val1, state_ws, coef, bincount, binlist);
    hipLaunchKernelGGL(k_state_final, dim3(B), dim3(256), 0, stream, state_ws, out);
    hipLaunchKernelGGL(k_accum, dim3(B * S / 4), dim3(256), 0, stream,
                       x, coef, bincount, binlist, val1);
    hipLaunchKernelGGL(k_qk, dim3(B * S / NR), dim3(256), 0, stream,
                       val1, pair_a, pair_b, q, kkT);
    hipLaunchKernelGGL(k_pscore, dim3(B * S / NI), dim3(512), 0, stream,
                       q, kkT, eidx, ew);
    hipLaunchKernelGGL(k_mix, dim3(B * S / 4), dim3(256), 0, stream,
                       eidx, ew, val1, out);
}

// Round 4
// 410.903 us; speedup vs baseline: 1.2646x; 1.0053x over previous
//
#include <hip/hip_runtime.h>
#include <cmath>

namespace {
constexpr int B = 8;
constexpr int T = 2048;
constexpr int D = 512;
constexpr int S = 2048;
constexpr int R = 64;
constexpr int KTOP = 16;
constexpr int NT = 8;    // tokens per block in score kernel (512 threads)
constexpr int NR = 16;   // rows per block in qk kernel
constexpr int NI = 8;    // rows per block in pscore kernel (512 threads)
constexpr int CAP = 256;     // bin capacity per (b,slot); overflow -> global list
constexpr int OVFCAP = 32768;

__device__ __forceinline__ float signf(float v) {
    return (v > 0.f) ? 1.f : ((v < 0.f) ? -1.f : 0.f);
}

// Exact top-16 by |value| (ties -> lower index) over a wave-private LDS row of S
// floats. Result: lane k (k<16) gets myg = signed value, myj = index, in exact
// descending (|v|, -j) order. Row contents are preserved on the fast path.
__device__ __forceinline__ void topk16_row(float* __restrict__ row,
                                           unsigned long long* __restrict__ cand,
                                           int lane, float& myg, int& myj) {
    const float4* p4 = (const float4*)row;
    // Phase 1: per-lane abs max over 32 elements
    float lmax = 0.f;
#pragma unroll
    for (int i = 0; i < 8; i++) {
        float4 v = p4[lane + 64 * i];
        lmax = fmaxf(lmax, fmaxf(fmaxf(fabsf(v.x), fabsf(v.y)),
                                 fmaxf(fabsf(v.z), fabsf(v.w))));
    }
    // Phase 2: bitonic sort (descending) of 64 lane maxes; t = 16th largest
    {
        float v = lmax;
#pragma unroll
        for (int size = 2; size <= 64; size <<= 1) {
#pragma unroll
            for (int stride = size >> 1; stride > 0; stride >>= 1) {
                float o = __shfl_xor(v, stride, 64);
                bool takeMax = ((lane & size) == 0) == ((lane & stride) == 0);
                v = takeMax ? fmaxf(v, o) : fminf(v, o);
            }
        }
        lmax = __shfl(v, 15);
    }
    float t = lmax;
    // Phase 3: count candidates with |v| >= t, prefix-sum, compact into cand[]
    int cnt = 0;
#pragma unroll
    for (int i = 0; i < 8; i++) {
        float4 v = p4[lane + 64 * i];
        cnt += (fabsf(v.x) >= t) + (fabsf(v.y) >= t) +
               (fabsf(v.z) >= t) + (fabsf(v.w) >= t);
    }
    int off = cnt;
#pragma unroll
    for (int d = 1; d < 64; d <<= 1) {
        int o = __shfl_up(off, d, 64);
        if (lane >= d) off += o;
    }
    int total = __shfl(off, 63);
    int base = off - cnt;

    if (total <= 64) {
        int pos = base;
#pragma unroll
        for (int i = 0; i < 8; i++) {
            float4 v = p4[lane + 64 * i];
            int jb = 4 * (lane + 64 * i);
            float c[4] = {v.x, v.y, v.z, v.w};
#pragma unroll
            for (int cc = 0; cc < 4; cc++) {
                if (fabsf(c[cc]) >= t) {
                    unsigned ab = __float_as_uint(c[cc]) & 0x7fffffffu;
                    cand[pos++] = ((unsigned long long)ab << 11) |
                                  (unsigned)(2047 - (jb + cc));
                }
            }
        }
        // Phase 4: bitonic sort (descending) of up to 64 u64 keys
        unsigned long long key = (lane < total) ? cand[lane] : 0ull;
#pragma unroll
        for (int size = 2; size <= 64; size <<= 1) {
#pragma unroll
            for (int stride = size >> 1; stride > 0; stride >>= 1) {
                unsigned long long o = __shfl_xor((long long)key, stride, 64);
                bool takeMax = ((lane & size) == 0) == ((lane & stride) == 0);
                key = (takeMax == (key > o)) ? key : o;
            }
        }
        myg = 0.f; myj = 0;
        if (lane < KTOP) {
            myj = 2047 - (int)(key & 2047ull);
            myg = row[myj];
        }
    } else {
        // Fallback (rare): 16 rounds of full-row argmax with removal
        myg = 0.f; myj = 0;
        for (int k = 0; k < KTOP; k++) {
            float bv = -1.f, bs = 0.f; int bj = 0;
#pragma unroll
            for (int i = 0; i < 8; i++) {
                float4 v = p4[lane + 64 * i];
                int jb = 4 * (lane + 64 * i);
                { float a = fabsf(v.x); if (a > bv) { bv = a; bs = v.x; bj = jb; } }
                { float a = fabsf(v.y); if (a > bv) { bv = a; bs = v.y; bj = jb + 1; } }
                { float a = fabsf(v.z); if (a > bv) { bv = a; bs = v.z; bj = jb + 2; } }
                { float a = fabsf(v.w); if (a > bv) { bv = a; bs = v.w; bj = jb + 3; } }
            }
#pragma unroll
            for (int off2 = 32; off2 > 0; off2 >>= 1) {
                float ov = __shfl_xor(bv, off2, 64);
                float os = __shfl_xor(bs, off2, 64);
                int   oj = __shfl_xor(bj, off2, 64);
                if (ov > bv || (ov == bv && oj < bj)) { bv = ov; bs = os; bj = oj; }
            }
            if (lane == k) { myg = bs; myj = bj; }
            if (lane == 0) row[bj] = 0.f;
        }
    }
}
} // namespace

// ---------- score stage: route scores -> per-wave topk -> bin lists ----------
// state_ws holds DELTAS only (memset 0 before this kernel).
// Overflow (bin > CAP) goes to a global list consumed by k_accum.
__global__ void __launch_bounds__(512, 4) k_score(const float* __restrict__ x,
                                                  const float* __restrict__ route_a,
                                                  const float* __restrict__ route_b,
                                                  float* __restrict__ state_ws,
                                                  float* __restrict__ coef,
                                                  int* __restrict__ bincount,
                                                  int* __restrict__ binlist,
                                                  int* __restrict__ ovf_cnt,
                                                  int* __restrict__ ovf_key,
                                                  float* __restrict__ ovf_c) {
    __shared__ __align__(16) char smem[NT * S * 4]; // 64 KB: xs -> red4 -> sc
    __shared__ __align__(16) float xr[NT][R];       // 2 KB
    __shared__ unsigned long long cand[NT][64];     // 4 KB
    float (*sc)[S] = (float(*)[S])smem;
    float (*xs)[D] = (float(*)[D])smem;             // overlay (x-load + acc read)
    float (*red4)[512] = (float(*)[512])smem;       // overlay (reduction only)

    int tid = threadIdx.x;
    int lane = tid & 63, wv = tid >> 6;
    int blk = ((blockIdx.x & 7) << 8) | (blockIdx.x >> 3);  // XCD k <-> b=k
    int tb = blk * NT;              // global token base (block never straddles b)
    int b = tb >> 11;               // T = 2048
    int t0 = tb & (T - 1);

    // load 8 x rows into LDS (1024 float4, 512 threads)
    {
        const float4* xg = (const float4*)(x + (size_t)tb * D);
        float4* xls = (float4*)smem;
        xls[tid] = xg[tid];
        xls[tid + 512] = xg[tid + 512];
    }
    __syncthreads();

    // x inverse norm for this wave's token, from LDS (x is read once, here)
    float xinv;
    {
        const float4* xst = (const float4*)&xs[wv][0];
        float4 x0 = xst[lane], x1 = xst[lane + 64];
        float ssx = x0.x * x0.x + x0.y * x0.y + x0.z * x0.z + x0.w * x0.w
                  + x1.x * x1.x + x1.y * x1.y + x1.z * x1.z + x1.w * x1.w;
#pragma unroll
        for (int off = 32; off > 0; off >>= 1) ssx += __shfl_xor(ssx, off, 64);
        xinv = 1.0f / (sqrtf(ssx) + 1e-6f);
    }

    // xr = x . route_a  (wave wv covers d in [wv*64, wv*64+64), r = lane)
    {
        int r = lane;
        float acc[NT];
#pragma unroll
        for (int tt = 0; tt < NT; tt++) acc[tt] = 0.f;
        for (int d0 = wv * 64; d0 < wv * 64 + 64; d0 += 4) {
            float a0 = route_a[(size_t)(d0 + 0) * R + r];
            float a1 = route_a[(size_t)(d0 + 1) * R + r];
            float a2 = route_a[(size_t)(d0 + 2) * R + r];
            float a3 = route_a[(size_t)(d0 + 3) * R + r];
#pragma unroll
            for (int tt = 0; tt < NT; tt++) {
                float4 xv = *(const float4*)&xs[tt][d0];
                acc[tt] += xv.x * a0 + xv.y * a1 + xv.z * a2 + xv.w * a3;
            }
        }
        __syncthreads();   // xs dead; red4 region writable
#pragma unroll
        for (int tt = 0; tt < NT; tt++) red4[tt][tid] = acc[tt];
        __syncthreads();
        {
            int tt2 = tid >> 6, r2 = tid & 63;
            float s = 0.f;
#pragma unroll
            for (int g = 0; g < 8; g++) s += red4[tt2][g * 64 + r2];
            xr[tt2][r2] = s;
        }
        __syncthreads();   // red4 dead; sc writable
    }

    // scores = xr . route_b  (float4 over s; 512 threads cover S/4 = 512)
    {
        const float4* rb4 = (const float4*)route_b;
        int j4 = tid;
        float4 acc[NT];
#pragma unroll
        for (int tt = 0; tt < NT; tt++) acc[tt] = make_float4(0.f, 0.f, 0.f, 0.f);
        for (int r0 = 0; r0 < R; r0 += 4) {
            float4 xv[NT];
#pragma unroll
            for (int tt = 0; tt < NT; tt++) xv[tt] = *(const float4*)&xr[tt][r0];
#define SCORE_STEP(dr, comp)                                                   \
            {                                                                  \
                float4 bv = rb4[(size_t)(r0 + dr) * (S / 4) + j4];             \
                _Pragma("unroll")                                              \
                for (int tt = 0; tt < NT; tt++) {                              \
                    float c = xv[tt].comp;                                     \
                    acc[tt].x += c * bv.x; acc[tt].y += c * bv.y;              \
                    acc[tt].z += c * bv.z; acc[tt].w += c * bv.w;              \
                }                                                              \
            }
            SCORE_STEP(0, x) SCORE_STEP(1, y) SCORE_STEP(2, z) SCORE_STEP(3, w)
#undef SCORE_STEP
        }
#pragma unroll
        for (int tt = 0; tt < NT; tt++)
            ((float4*)&sc[tt][0])[j4] = acc[tt];
    }
    __syncthreads();

    // ---- per-wave from here: wave wv owns token tt = wv ----
    int tt = wv;
    int tloc = t0 + tt;
    int tglob = tb + tt;

    float myg; int myj;
    topk16_row(&sc[tt][0], &cand[wv][0], lane, myg, myj);

    // signed-abs-softmax over the 16 winners (lane k holds winner k)
    float m = __shfl(fabsf(myg), 0);
    float e = (lane < KTOP) ? expf(fabsf(myg) - m) : 0.f;
    float esum = e;
#pragma unroll
    for (int off = 8; off > 0; off >>= 1) esum += __shfl_xor(esum, off, 64);
    esum = __shfl(esum, 0);
    float w = signf(myg) * e / esum;
    float coefv = w * xinv;

    if (lane < KTOP) {
        float sp = (myg > 20.f) ? myg : log1pf(expf(myg));
        atomicAdd(&state_ws[(size_t)b * S + myj], sp);
        int pos = atomicAdd(&bincount[(size_t)b * S + myj], 1);
        if (pos < CAP) {
            binlist[((size_t)b * S + myj) * CAP + pos] = (tloc << 4) | lane;
            coef[(size_t)tglob * KTOP + lane] = coefv;
        } else {
            // overflow (essentially never): append to global list
            int i = atomicAdd(ovf_cnt, 1);
            if (i < OVFCAP) {
                ovf_key[i] = ((b * S + myj) << 11) | tloc;  // 14b row | 11b tloc
                ovf_c[i] = coefv;
            }
        }
    }
}

// ---------- accumulate: val1[row] = unit_norm(unit_norm(init_val) + sum c*x) ---
__global__ void __launch_bounds__(256) k_accum(const float* __restrict__ x,
                                               const float* __restrict__ init_val,
                                               const float* __restrict__ coef,
                                               const int* __restrict__ bincount,
                                               const int* __restrict__ binlist,
                                               const int* __restrict__ ovf_cnt,
                                               const int* __restrict__ ovf_key,
                                               const float* __restrict__ ovf_c,
                                               float* __restrict__ val1) {
    int lane = threadIdx.x & 63, wv = threadIdx.x >> 6;
    int blk = ((blockIdx.x & 7) << 9) | (blockIdx.x >> 3);  // XCD k <-> b=k
    int row = blk * 4 + wv;             // row = b*S + s
    int b = row >> 11;                  // S = 2048
    int s_idx = row & (S - 1);

    // base = unit_norm(init_val[s]) computed in-register (bit-identical to the
    // old k_bcast pass; init_val is 4 MB -> L3-hot)
    const float4* src = (const float4*)(init_val + (size_t)s_idx * D);
    float4 a0 = src[lane], a1 = src[lane + 64];
    {
        float ss0 = a0.x * a0.x + a0.y * a0.y + a0.z * a0.z + a0.w * a0.w
                  + a1.x * a1.x + a1.y * a1.y + a1.z * a1.z + a1.w * a1.w;
#pragma unroll
        for (int off = 32; off > 0; off >>= 1) ss0 += __shfl_xor(ss0, off, 64);
        float bsc = 1.0f / (sqrtf(ss0) + 1e-6f);
        a0.x *= bsc; a0.y *= bsc; a0.z *= bsc; a0.w *= bsc;
        a1.x *= bsc; a1.y *= bsc; a1.z *= bsc; a1.w *= bsc;
    }

    int n = bincount[row]; if (n > CAP) n = CAP;
    const int* lp = binlist + (size_t)row * CAP;
    for (int base = 0; base < n; base += 64) {
        int mm = n - base; if (mm > 64) mm = 64;
        int ent = 0; float cc = 0.f;
        if (lane < mm) {
            ent = lp[base + lane];
            cc = coef[((size_t)b * T + (ent >> 4)) * KTOP + (ent & 15)];
        }
        // 1-deep software pipeline over the gather loop
        int e0 = __shfl(ent, 0);
        const float4* xp4 = (const float4*)(x + ((size_t)b * T + (e0 >> 4)) * D);
        float4 v0 = xp4[lane], v1 = xp4[lane + 64];
        for (int k = 0; k < mm; k++) {
            float c = __shfl(cc, k);
            float4 c0 = v0, c1 = v1;
            if (k + 1 < mm) {
                int e2 = __shfl(ent, k + 1);
                const float4* np4 = (const float4*)(x + ((size_t)b * T + (e2 >> 4)) * D);
                v0 = np4[lane]; v1 = np4[lane + 64];
            }
            a0.x += c * c0.x; a0.y += c * c0.y; a0.z += c * c0.z; a0.w += c * c0.w;
            a1.x += c * c1.x; a1.y += c * c1.y; a1.z += c * c1.z; a1.w += c * c1.w;
        }
    }

    // overflow list (cold path; one uniform load when empty)
    int oc = *ovf_cnt; if (oc > OVFCAP) oc = OVFCAP;
    for (int i = 0; i < oc; i++) {
        int key = ovf_key[i];
        if ((key >> 11) == row) {
            float c = ovf_c[i];
            int tg = ((row >> 11) << 11) | (key & 2047);   // b*T + tloc
            const float4* xp4 = (const float4*)(x + (size_t)tg * D);
            float4 v0 = xp4[lane], v1 = xp4[lane + 64];
            a0.x += c * v0.x; a0.y += c * v0.y; a0.z += c * v0.z; a0.w += c * v0.w;
            a1.x += c * v1.x; a1.y += c * v1.y; a1.z += c * v1.z; a1.w += c * v1.w;
        }
    }

    float ss = a0.x * a0.x + a0.y * a0.y + a0.z * a0.z + a0.w * a0.w
             + a1.x * a1.x + a1.y * a1.y + a1.z * a1.z + a1.w * a1.w;
#pragma unroll
    for (int off = 32; off > 0; off >>= 1) ss += __shfl_xor(ss, off, 64);
    float sc = 1.0f / (sqrtf(ss) + 1e-6f);
    a0.x *= sc; a0.y *= sc; a0.z *= sc; a0.w *= sc;
    a1.x *= sc; a1.y *= sc; a1.z *= sc; a1.w *= sc;
    float4* vp4 = (float4*)(val1 + (size_t)row * D);
    vp4[lane] = a0; vp4[lane + 64] = a1;
}

// ---------- state reduce: base softmax + per-b (m, 1/sum) of base+delta ------
// One block, 512 threads. Replaces k_init_state + most of k_state_final.
__global__ void __launch_bounds__(512) k_state_red(const float* __restrict__ init_state,
                                                   const float* __restrict__ state_ws,
                                                   float* base_ws,
                                                   float* sm_m, float* sm_inv) {
    __shared__ float red[16];
    __shared__ float base_lds[S];   // 8 KB
    int tid = threadIdx.x, lane = tid & 63, wv = tid >> 6;

    // Phase A: base = sign * softmax(|init_state|)  (2048 values, 4 per thread)
    float4 v = ((const float4*)init_state)[tid];
    float m = fmaxf(fmaxf(fabsf(v.x), fabsf(v.y)), fmaxf(fabsf(v.z), fabsf(v.w)));
#pragma unroll
    for (int off = 32; off > 0; off >>= 1) m = fmaxf(m, __shfl_xor(m, off, 64));
    if (lane == 0) red[wv] = m;
    __syncthreads();
    float M = red[0];
#pragma unroll
    for (int i = 1; i < 8; i++) M = fmaxf(M, red[i]);
    __syncthreads();
    float s = expf(fabsf(v.x) - M) + expf(fabsf(v.y) - M) +
              expf(fabsf(v.z) - M) + expf(fabsf(v.w) - M);
#pragma unroll
    for (int off = 32; off > 0; off >>= 1) s += __shfl_xor(s, off, 64);
    if (lane == 0) red[wv] = s;
    __syncthreads();
    float SUM = 0.f;
#pragma unroll
    for (int i = 0; i < 8; i++) SUM += red[i];
    float inv = 1.0f / SUM;
    float4 bo;
    bo.x = signf(v.x) * expf(fabsf(v.x) - M) * inv;
    bo.y = signf(v.y) * expf(fabsf(v.y) - M) * inv;
    bo.z = signf(v.z) * expf(fabsf(v.z) - M) * inv;
    bo.w = signf(v.w) * expf(fabsf(v.w) - M) * inv;
    ((float4*)base_ws)[tid] = bo;
    ((float4*)base_lds)[tid] = bo;
    __syncthreads();

    // Phase B: wave wv = b; combined = base + delta; per-b max & expsum
    int b = wv;
    const float4* dp = (const float4*)(state_ws + (size_t)b * S);
    const float4* bp = (const float4*)base_lds;
    float4 c[8];
    float vm = 0.f;
#pragma unroll
    for (int i = 0; i < 8; i++) {
        float4 dv = dp[lane + 64 * i];
        float4 bv = bp[lane + 64 * i];
        c[i].x = bv.x + dv.x; c[i].y = bv.y + dv.y;
        c[i].z = bv.z + dv.z; c[i].w = bv.w + dv.w;
        vm = fmaxf(vm, fmaxf(fmaxf(fabsf(c[i].x), fabsf(c[i].y)),
                             fmaxf(fabsf(c[i].z), fabsf(c[i].w))));
    }
#pragma unroll
    for (int off = 32; off > 0; off >>= 1) vm = fmaxf(vm, __shfl_xor(vm, off, 64));
    float sum = 0.f;
#pragma unroll
    for (int i = 0; i < 8; i++) {
        sum += expf(fabsf(c[i].x) - vm) + expf(fabsf(c[i].y) - vm) +
               expf(fabsf(c[i].z) - vm) + expf(fabsf(c[i].w) - vm);
    }
#pragma unroll
    for (int off = 32; off > 0; off >>= 1) sum += __shfl_xor(sum, off, 64);
    if (lane == 0) { sm_m[b] = vm; sm_inv[b] = 1.0f / sum; }
}

// ---------- q / kT projections ----------
__global__ void __launch_bounds__(256) k_qk(const float* __restrict__ val1,
                                            const float* __restrict__ pair_a,
                                            const float* __restrict__ pair_b,
                                            float* __restrict__ q,
                                            float* __restrict__ kkT) {
    __shared__ __align__(16) float vrow[NR][D];   // 32 KB
    __shared__ float redq[256];
    __shared__ float redk[256];
    int tid = threadIdx.x;
    int blk = ((blockIdx.x & 7) << 7) | (blockIdx.x >> 3);  // XCD k <-> b=k
    int rowbase = blk * NR;           // = b*S + sbase (never straddles b)
    int b = rowbase >> 11;
    int sbase = rowbase & (S - 1);
    {
        const float4* gv = (const float4*)(val1 + (size_t)rowbase * D);
        float4* lv = (float4*)&vrow[0][0];
        for (int i = tid; i < NR * D / 4; i += 256) lv[i] = gv[i];
    }
    __syncthreads();
    int r = tid & 63, grp = tid >> 6;
    float accq[NR], acck[NR];
#pragma unroll
    for (int rr = 0; rr < NR; rr++) { accq[rr] = 0.f; acck[rr] = 0.f; }
    for (int d0 = grp * 128; d0 < grp * 128 + 128; d0 += 4) {
#pragma unroll
        for (int dd = 0; dd < 4; dd++) {
            float a  = pair_a[(size_t)(d0 + dd) * R + r];
            float bb = pair_b[(size_t)(d0 + dd) * R + r];
#pragma unroll
            for (int rr = 0; rr < NR; rr++) {
                float v = vrow[rr][d0 + dd];
                accq[rr] += v * a;
                acck[rr] += v * bb;
            }
        }
    }
    for (int rr = 0; rr < NR; rr++) {
        redq[tid] = accq[rr]; redk[tid] = acck[rr];
        __syncthreads();
        if (tid < 64) {
            float qv = redq[tid] + redq[tid + 64] + redq[tid + 128] + redq[tid + 192];
            float kv = redk[tid] + redk[tid + 64] + redk[tid + 128] + redk[tid + 192];
            q[(size_t)(rowbase + rr) * R + tid] = qv;
            kkT[((size_t)b * R + tid) * S + (sbase + rr)] = kv;
        }
        __syncthreads();
    }
}

// ---------- pscore: p = q.kT (float4), per-wave topk -> eidx/ew ----------
__global__ void __launch_bounds__(512) k_pscore(const float* __restrict__ q,
                                                const float* __restrict__ kkT,
                                                int* __restrict__ eidx,
                                                float* __restrict__ ew_g) {
    __shared__ __align__(16) float prow[NI][S];   // 64 KB
    __shared__ __align__(16) float qrow[NI][R];   // 2 KB
    __shared__ unsigned long long cand[NI][64];   // 4 KB

    int tid = threadIdx.x;
    int lane = tid & 63, wv = tid >> 6;
    int blk = ((blockIdx.x & 7) << 8) | (blockIdx.x >> 3);  // XCD k <-> b=k
    int ibase = blk * NI;            // global row base (never straddles b)
    int b = ibase >> 11;             // S = 2048

    {
        int rr = tid >> 6, r = tid & 63;
        qrow[rr][r] = q[(size_t)(ibase + rr) * R + r];
    }
    __syncthreads();

    // p rows (float4 over j; kkT slice reused by 8 rows)
    {
        const float4* kk4 = (const float4*)(kkT + (size_t)b * R * S);
        int j4 = tid;                // 512 threads cover S/4 = 512
        float4 acc[NI];
#pragma unroll
        for (int rr = 0; rr < NI; rr++) acc[rr] = make_float4(0.f, 0.f, 0.f, 0.f);
        for (int r0 = 0; r0 < R; r0 += 4) {
            float4 qv[NI];
#pragma unroll
            for (int rr = 0; rr < NI; rr++) qv[rr] = *(const float4*)&qrow[rr][r0];
#define P_STEP(dr, comp)                                                       \
            {                                                                  \
                float4 kv = kk4[(size_t)(r0 + dr) * (S / 4) + j4];             \
                _Pragma("unroll")                                              \
                for (int rr = 0; rr < NI; rr++) {                              \
                    float c = qv[rr].comp;                                     \
                    acc[rr].x += c * kv.x; acc[rr].y += c * kv.y;              \
                    acc[rr].z += c * kv.z; acc[rr].w += c * kv.w;              \
                }                                                              \
            }
            P_STEP(0, x) P_STEP(1, y) P_STEP(2, z) P_STEP(3, w)
#undef P_STEP
        }
#pragma unroll
        for (int rr = 0; rr < NI; rr++)
            ((float4*)&prow[rr][0])[j4] = acc[rr];
    }
    __syncthreads();

    // ---- per-wave topk on row ibase + wv (8 waves, 8 rows) ----
    int row = ibase + wv;
    float myg; int myj;
    topk16_row(&prow[wv][0], &cand[wv][0], lane, myg, myj);

    float m = __shfl(fabsf(myg), 0);
    float e = (lane < KTOP) ? expf(fabsf(myg) - m) : 0.f;
    float esum = e;
#pragma unroll
    for (int off = 8; off > 0; off >>= 1) esum += __shfl_xor(esum, off, 64);
    esum = __shfl(esum, 0);
    float myw = signf(myg) * e / esum;

    if (lane < KTOP) {
        eidx[(size_t)row * KTOP + lane] = myj;
        ew_g[(size_t)row * KTOP + lane] = myw;
    }
}

// ---------- mix: gather neighbors, residual, unit-norm, full out row ----------
__global__ void __launch_bounds__(256) k_mix(const int* __restrict__ eidx,
                                             const float* __restrict__ ew_g,
                                             const float* __restrict__ val1,
                                             const float* __restrict__ base_ws,
                                             const float* __restrict__ state_ws,
                                             const float* __restrict__ sm_m,
                                             const float* __restrict__ sm_inv,
                                             float* __restrict__ out) {
    int lane = threadIdx.x & 63, wv = threadIdx.x >> 6;
    int blk = ((blockIdx.x & 7) << 9) | (blockIdx.x >> 3);  // XCD k <-> b=k
    int row = blk * 4 + wv;
    int b = row >> 11;

    int e_i = 0; float e_w = 0.f;
    if (lane < KTOP) {
        e_i = eidx[(size_t)row * KTOP + lane];
        e_w = ew_g[(size_t)row * KTOP + lane];
    }

    const float4* self4 = (const float4*)(val1 + (size_t)row * D);
    float4 a0 = self4[lane], a1 = self4[lane + 64];
#pragma unroll
    for (int k = 0; k < KTOP; k++) {
        int j = __shfl(e_i, k);
        float w = __shfl(e_w, k);
        const float4* nb4 = (const float4*)(val1 + ((size_t)b * S + j) * D);
        float4 v0 = nb4[lane], v1 = nb4[lane + 64];
        a0.x += w * v0.x; a0.y += w * v0.y; a0.z += w * v0.z; a0.w += w * v0.w;
        a1.x += w * v1.x; a1.y += w * v1.y; a1.z += w * v1.z; a1.w += w * v1.w;
    }
    float ss = a0.x * a0.x + a0.y * a0.y + a0.z * a0.z + a0.w * a0.w
             + a1.x * a1.x + a1.y * a1.y + a1.z * a1.z + a1.w * a1.w;
#pragma unroll
    for (int off = 32; off > 0; off >>= 1) ss += __shfl_xor(ss, off, 64);
    float sc = 1.0f / (sqrtf(ss) + 1e-6f);
    float* op = out + (size_t)row * (D + 1) + 1;
    int d0 = 4 * lane;
    op[d0 + 0] = a0.x * sc; op[d0 + 1] = a0.y * sc;
    op[d0 + 2] = a0.z * sc; op[d0 + 3] = a0.w * sc;
    op[256 + d0 + 0] = a1.x * sc; op[256 + d0 + 1] = a1.y * sc;
    op[256 + d0 + 2] = a1.z * sc; op[256 + d0 + 3] = a1.w * sc;

    // state output column (was k_state_final)
    if (lane == 0) {
        float vv = base_ws[row & (S - 1)] + state_ws[row];
        out[(size_t)row * (D + 1)] =
            signf(vv) * expf(fabsf(vv) - sm_m[b]) * sm_inv[b];
    }
}

extern "C" void kernel_launch(void* const* d_in, const int* in_sizes, int n_in,
                              void* d_out, int out_size, void* d_ws, size_t ws_size,
                              hipStream_t stream) {
    (void)in_sizes; (void)n_in; (void)out_size; (void)ws_size;
    const float* x          = (const float*)d_in[0];
    const float* init_state = (const float*)d_in[1];
    const float* init_val   = (const float*)d_in[2];
    const float* route_a    = (const float*)d_in[3];
    const float* route_b    = (const float*)d_in[4];
    const float* pair_a     = (const float*)d_in[5];
    const float* pair_b     = (const float*)d_in[6];
    float* out = (float*)d_out;

    float* ws       = (float*)d_ws;
    float* val1     = ws;                             // B*S*D
    float* q        = val1 + (size_t)B * S * D;       // B*S*R
    float* kkT      = q    + (size_t)B * S * R;       // B*R*S
    float* coef     = kkT  + (size_t)B * R * S;       // B*T*K
    int*   binlist  = (int*)(coef + (size_t)B * T * KTOP);   // B*S*CAP
    // --- zero region (one memset): state deltas + bincount + ovf_cnt ---
    float* state_ws = (float*)(binlist + (size_t)B * S * CAP);  // B*S
    int*   bincount = (int*)(state_ws + (size_t)B * S);         // B*S
    int*   ovf_cnt  = bincount + (size_t)B * S;                 // 16 (pad)
    // --- end zero region ---
    int*   ovf_key  = ovf_cnt + 16;                             // OVFCAP
    float* ovf_c    = (float*)(ovf_key + OVFCAP);               // OVFCAP
    float* base_ws  = ovf_c + OVFCAP;                           // S
    float* sm_m     = base_ws + S;                              // B
    float* sm_inv   = sm_m + B;                                 // B
    // eidx/ew reuse binlist space (binlist dead after k_accum)
    int*   eidx     = binlist;                                  // B*S*K
    float* ew       = (float*)(binlist + (size_t)B * S * KTOP); // B*S*K

    hipMemsetAsync(state_ws, 0, (size_t)(2 * B * S + 16) * sizeof(int), stream);
    hipLaunchKernelGGL(k_score, dim3(B * T / NT), dim3(512), 0, stream,
                       x, route_a, route_b, state_ws, coef, bincount, binlist,
                       ovf_cnt, ovf_key, ovf_c);
    hipLaunchKernelGGL(k_state_red, dim3(1), dim3(512), 0, stream,
                       init_state, state_ws, base_ws, sm_m, sm_inv);
    hipLaunchKernelGGL(k_accum, dim3(B * S / 4), dim3(256), 0, stream,
                       x, init_val, coef, bincount, binlist,
                       ovf_cnt, ovf_key, ovf_c, val1);
    hipLaunchKernelGGL(k_qk, dim3(B * S / NR), dim3(256), 0, stream,
                       val1, pair_a, pair_b, q, kkT);
    hipLaunchKernelGGL(k_pscore, dim3(B * S / NI), dim3(512), 0, stream,
                       q, kkT, eidx, ew);
    hipLaunchKernelGGL(k_mix, dim3(B * S / 4), dim3(256), 0, stream,
                       eidx, ew, val1, base_ws, state_ws, sm_m, sm_inv, out);
}

// Round 5
// 392.832 us; speedup vs baseline: 1.3228x; 1.0460x over previous
//
#include <hip/hip_runtime.h>
#include <cmath>

namespace {
constexpr int B = 8;
constexpr int T = 2048;
constexpr int D = 512;
constexpr int S = 2048;
constexpr int R = 64;
constexpr int KTOP = 16;
constexpr int NT = 8;    // tokens per block in score kernel (512 threads)
constexpr int NI = 8;    // rows per block in pscore kernel (512 threads)
constexpr int CAP = 256;     // bin capacity per (b,slot); overflow -> global list
constexpr int OVFCAP = 32768;

__device__ __forceinline__ float signf(float v) {
    return (v > 0.f) ? 1.f : ((v < 0.f) ? -1.f : 0.f);
}

// Exact top-16 by |value| (ties -> lower index) over a wave-private LDS row of S
// floats. Result: lane k (k<16) gets myg = signed value, myj = index, in exact
// descending (|v|, -j) order. Row contents are preserved on the fast path.
__device__ __forceinline__ void topk16_row(float* __restrict__ row,
                                           unsigned long long* __restrict__ cand,
                                           int lane, float& myg, int& myj) {
    const float4* p4 = (const float4*)row;
    // Phase 1: per-lane abs max over 32 elements
    float lmax = 0.f;
#pragma unroll
    for (int i = 0; i < 8; i++) {
        float4 v = p4[lane + 64 * i];
        lmax = fmaxf(lmax, fmaxf(fmaxf(fabsf(v.x), fabsf(v.y)),
                                 fmaxf(fabsf(v.z), fabsf(v.w))));
    }
    // Phase 2: bitonic sort (descending) of 64 lane maxes; t = 16th largest
    {
        float v = lmax;
#pragma unroll
        for (int size = 2; size <= 64; size <<= 1) {
#pragma unroll
            for (int stride = size >> 1; stride > 0; stride >>= 1) {
                float o = __shfl_xor(v, stride, 64);
                bool takeMax = ((lane & size) == 0) == ((lane & stride) == 0);
                v = takeMax ? fmaxf(v, o) : fminf(v, o);
            }
        }
        lmax = __shfl(v, 15);
    }
    float t = lmax;
    // Phase 3: count candidates with |v| >= t, prefix-sum, compact into cand[]
    int cnt = 0;
#pragma unroll
    for (int i = 0; i < 8; i++) {
        float4 v = p4[lane + 64 * i];
        cnt += (fabsf(v.x) >= t) + (fabsf(v.y) >= t) +
               (fabsf(v.z) >= t) + (fabsf(v.w) >= t);
    }
    int off = cnt;
#pragma unroll
    for (int d = 1; d < 64; d <<= 1) {
        int o = __shfl_up(off, d, 64);
        if (lane >= d) off += o;
    }
    int total = __shfl(off, 63);
    int base = off - cnt;

    if (total <= 64) {
        int pos = base;
#pragma unroll
        for (int i = 0; i < 8; i++) {
            float4 v = p4[lane + 64 * i];
            int jb = 4 * (lane + 64 * i);
            float c[4] = {v.x, v.y, v.z, v.w};
#pragma unroll
            for (int cc = 0; cc < 4; cc++) {
                if (fabsf(c[cc]) >= t) {
                    unsigned ab = __float_as_uint(c[cc]) & 0x7fffffffu;
                    cand[pos++] = ((unsigned long long)ab << 11) |
                                  (unsigned)(2047 - (jb + cc));
                }
            }
        }
        // Phase 4: bitonic sort (descending) of up to 64 u64 keys
        unsigned long long key = (lane < total) ? cand[lane] : 0ull;
#pragma unroll
        for (int size = 2; size <= 64; size <<= 1) {
#pragma unroll
            for (int stride = size >> 1; stride > 0; stride >>= 1) {
                unsigned long long o = __shfl_xor((long long)key, stride, 64);
                bool takeMax = ((lane & size) == 0) == ((lane & stride) == 0);
                key = (takeMax == (key > o)) ? key : o;
            }
        }
        myg = 0.f; myj = 0;
        if (lane < KTOP) {
            myj = 2047 - (int)(key & 2047ull);
            myg = row[myj];
        }
    } else {
        // Fallback (rare): 16 rounds of full-row argmax with removal
        myg = 0.f; myj = 0;
        for (int k = 0; k < KTOP; k++) {
            float bv = -1.f, bs = 0.f; int bj = 0;
#pragma unroll
            for (int i = 0; i < 8; i++) {
                float4 v = p4[lane + 64 * i];
                int jb = 4 * (lane + 64 * i);
                { float a = fabsf(v.x); if (a > bv) { bv = a; bs = v.x; bj = jb; } }
                { float a = fabsf(v.y); if (a > bv) { bv = a; bs = v.y; bj = jb + 1; } }
                { float a = fabsf(v.z); if (a > bv) { bv = a; bs = v.z; bj = jb + 2; } }
                { float a = fabsf(v.w); if (a > bv) { bv = a; bs = v.w; bj = jb + 3; } }
            }
#pragma unroll
            for (int off2 = 32; off2 > 0; off2 >>= 1) {
                float ov = __shfl_xor(bv, off2, 64);
                float os = __shfl_xor(bs, off2, 64);
                int   oj = __shfl_xor(bj, off2, 64);
                if (ov > bv || (ov == bv && oj < bj)) { bv = ov; bs = os; bj = oj; }
            }
            if (lane == k) { myg = bs; myj = bj; }
            if (lane == 0) row[bj] = 0.f;
        }
    }
}
} // namespace

// ---------- score stage: route scores -> per-wave topk -> bin lists ----------
// state_ws holds DELTAS only (memset 0 before this kernel).
// Overflow (bin > CAP) goes to a global list consumed by k_accum_qk.
__global__ void __launch_bounds__(512, 4) k_score(const float* __restrict__ x,
                                                  const float* __restrict__ route_a,
                                                  const float* __restrict__ route_b,
                                                  float* __restrict__ state_ws,
                                                  float* __restrict__ coef,
                                                  int* __restrict__ bincount,
                                                  int* __restrict__ binlist,
                                                  int* __restrict__ ovf_cnt,
                                                  int* __restrict__ ovf_key,
                                                  float* __restrict__ ovf_c) {
    __shared__ __align__(16) char smem[NT * S * 4]; // 64 KB: xs -> red4 -> sc
    __shared__ __align__(16) float xr[NT][R];       // 2 KB
    __shared__ unsigned long long cand[NT][64];     // 4 KB
    float (*sc)[S] = (float(*)[S])smem;
    float (*xs)[D] = (float(*)[D])smem;             // overlay (x-load + acc read)
    float (*red4)[512] = (float(*)[512])smem;       // overlay (reduction only)

    int tid = threadIdx.x;
    int lane = tid & 63, wv = tid >> 6;
    int blk = ((blockIdx.x & 7) << 8) | (blockIdx.x >> 3);  // XCD k <-> b=k
    int tb = blk * NT;              // global token base (block never straddles b)
    int b = tb >> 11;               // T = 2048
    int t0 = tb & (T - 1);

    // load 8 x rows into LDS (1024 float4, 512 threads)
    {
        const float4* xg = (const float4*)(x + (size_t)tb * D);
        float4* xls = (float4*)smem;
        xls[tid] = xg[tid];
        xls[tid + 512] = xg[tid + 512];
    }
    __syncthreads();

    // x inverse norm for this wave's token, from LDS (x is read once, here)
    float xinv;
    {
        const float4* xst = (const float4*)&xs[wv][0];
        float4 x0 = xst[lane], x1 = xst[lane + 64];
        float ssx = x0.x * x0.x + x0.y * x0.y + x0.z * x0.z + x0.w * x0.w
                  + x1.x * x1.x + x1.y * x1.y + x1.z * x1.z + x1.w * x1.w;
#pragma unroll
        for (int off = 32; off > 0; off >>= 1) ssx += __shfl_xor(ssx, off, 64);
        xinv = 1.0f / (sqrtf(ssx) + 1e-6f);
    }

    // xr = x . route_a  (wave wv covers d in [wv*64, wv*64+64), r = lane)
    {
        int r = lane;
        float acc[NT];
#pragma unroll
        for (int tt = 0; tt < NT; tt++) acc[tt] = 0.f;
        for (int d0 = wv * 64; d0 < wv * 64 + 64; d0 += 4) {
            float a0 = route_a[(size_t)(d0 + 0) * R + r];
            float a1 = route_a[(size_t)(d0 + 1) * R + r];
            float a2 = route_a[(size_t)(d0 + 2) * R + r];
            float a3 = route_a[(size_t)(d0 + 3) * R + r];
#pragma unroll
            for (int tt = 0; tt < NT; tt++) {
                float4 xv = *(const float4*)&xs[tt][d0];
                acc[tt] += xv.x * a0 + xv.y * a1 + xv.z * a2 + xv.w * a3;
            }
        }
        __syncthreads();   // xs dead; red4 region writable
#pragma unroll
        for (int tt = 0; tt < NT; tt++) red4[tt][tid] = acc[tt];
        __syncthreads();
        {
            int tt2 = tid >> 6, r2 = tid & 63;
            float s = 0.f;
#pragma unroll
            for (int g = 0; g < 8; g++) s += red4[tt2][g * 64 + r2];
            xr[tt2][r2] = s;
        }
        __syncthreads();   // red4 dead; sc writable
    }

    // scores = xr . route_b  (float4 over s; 512 threads cover S/4 = 512)
    {
        const float4* rb4 = (const float4*)route_b;
        int j4 = tid;
        float4 acc[NT];
#pragma unroll
        for (int tt = 0; tt < NT; tt++) acc[tt] = make_float4(0.f, 0.f, 0.f, 0.f);
        for (int r0 = 0; r0 < R; r0 += 4) {
            float4 xv[NT];
#pragma unroll
            for (int tt = 0; tt < NT; tt++) xv[tt] = *(const float4*)&xr[tt][r0];
#define SCORE_STEP(dr, comp)                                                   \
            {                                                                  \
                float4 bv = rb4[(size_t)(r0 + dr) * (S / 4) + j4];             \
                _Pragma("unroll")                                              \
                for (int tt = 0; tt < NT; tt++) {                              \
                    float c = xv[tt].comp;                                     \
                    acc[tt].x += c * bv.x; acc[tt].y += c * bv.y;              \
                    acc[tt].z += c * bv.z; acc[tt].w += c * bv.w;              \
                }                                                              \
            }
            SCORE_STEP(0, x) SCORE_STEP(1, y) SCORE_STEP(2, z) SCORE_STEP(3, w)
#undef SCORE_STEP
        }
#pragma unroll
        for (int tt = 0; tt < NT; tt++)
            ((float4*)&sc[tt][0])[j4] = acc[tt];
    }
    __syncthreads();

    // ---- per-wave from here: wave wv owns token tt = wv ----
    int tt = wv;
    int tloc = t0 + tt;
    int tglob = tb + tt;

    float myg; int myj;
    topk16_row(&sc[tt][0], &cand[wv][0], lane, myg, myj);

    // signed-abs-softmax over the 16 winners (lane k holds winner k)
    float m = __shfl(fabsf(myg), 0);
    float e = (lane < KTOP) ? expf(fabsf(myg) - m) : 0.f;
    float esum = e;
#pragma unroll
    for (int off = 8; off > 0; off >>= 1) esum += __shfl_xor(esum, off, 64);
    esum = __shfl(esum, 0);
    float w = signf(myg) * e / esum;
    float coefv = w * xinv;

    if (lane < KTOP) {
        float sp = (myg > 20.f) ? myg : log1pf(expf(myg));
        atomicAdd(&state_ws[(size_t)b * S + myj], sp);
        int pos = atomicAdd(&bincount[(size_t)b * S + myj], 1);
        if (pos < CAP) {
            binlist[((size_t)b * S + myj) * CAP + pos] = (tloc << 4) | lane;
            coef[(size_t)tglob * KTOP + lane] = coefv;
        } else {
            // overflow (essentially never): append to global list
            int i = atomicAdd(ovf_cnt, 1);
            if (i < OVFCAP) {
                ovf_key[i] = ((b * S + myj) << 11) | tloc;  // 14b row | 11b tloc
                ovf_c[i] = coefv;
            }
        }
    }
}

// ---------- accum+qk: val1 = unit_norm(base + sum c*x); q/kkT projections ----
// Fusion of the former k_accum and k_qk (NR=4). The projection keeps k_qk's
// exact d-partition and reduce order -> bit-identical q/kkT.
__global__ void __launch_bounds__(256) k_accum_qk(const float* __restrict__ x,
                                                  const float* __restrict__ init_val,
                                                  const float* __restrict__ coef,
                                                  const int* __restrict__ bincount,
                                                  const int* __restrict__ binlist,
                                                  const int* __restrict__ ovf_cnt,
                                                  const int* __restrict__ ovf_key,
                                                  const float* __restrict__ ovf_c,
                                                  const float* __restrict__ pair_a,
                                                  const float* __restrict__ pair_b,
                                                  float* __restrict__ val1,
                                                  float* __restrict__ q,
                                                  float* __restrict__ kkT) {
    __shared__ __align__(16) float vrow[4][D];    // 8 KB
    __shared__ float redq[4][256];                // 4 KB
    __shared__ float redk[4][256];                // 4 KB

    int tid = threadIdx.x;
    int lane = tid & 63, wv = tid >> 6;
    int blk = ((blockIdx.x & 7) << 9) | (blockIdx.x >> 3);  // XCD k <-> b=k
    int rowbase = blk * 4;
    int row = rowbase + wv;             // row = b*S + s
    int b = row >> 11;                  // S = 2048
    int s_idx = row & (S - 1);
    int sbase = rowbase & (S - 1);

    // base = unit_norm(init_val[s]) computed in-register
    const float4* src = (const float4*)(init_val + (size_t)s_idx * D);
    float4 a0 = src[lane], a1 = src[lane + 64];
    {
        float ss0 = a0.x * a0.x + a0.y * a0.y + a0.z * a0.z + a0.w * a0.w
                  + a1.x * a1.x + a1.y * a1.y + a1.z * a1.z + a1.w * a1.w;
#pragma unroll
        for (int off = 32; off > 0; off >>= 1) ss0 += __shfl_xor(ss0, off, 64);
        float bsc = 1.0f / (sqrtf(ss0) + 1e-6f);
        a0.x *= bsc; a0.y *= bsc; a0.z *= bsc; a0.w *= bsc;
        a1.x *= bsc; a1.y *= bsc; a1.z *= bsc; a1.w *= bsc;
    }

    int n = bincount[row]; if (n > CAP) n = CAP;
    const int* lp = binlist + (size_t)row * CAP;
    for (int base = 0; base < n; base += 64) {
        int mm = n - base; if (mm > 64) mm = 64;
        int ent = 0; float cc = 0.f;
        if (lane < mm) {
            ent = lp[base + lane];
            cc = coef[((size_t)b * T + (ent >> 4)) * KTOP + (ent & 15)];
        }
        // 1-deep software pipeline over the gather loop
        int e0 = __shfl(ent, 0);
        const float4* xp4 = (const float4*)(x + ((size_t)b * T + (e0 >> 4)) * D);
        float4 v0 = xp4[lane], v1 = xp4[lane + 64];
        for (int k = 0; k < mm; k++) {
            float c = __shfl(cc, k);
            float4 c0 = v0, c1 = v1;
            if (k + 1 < mm) {
                int e2 = __shfl(ent, k + 1);
                const float4* np4 = (const float4*)(x + ((size_t)b * T + (e2 >> 4)) * D);
                v0 = np4[lane]; v1 = np4[lane + 64];
            }
            a0.x += c * c0.x; a0.y += c * c0.y; a0.z += c * c0.z; a0.w += c * c0.w;
            a1.x += c * c1.x; a1.y += c * c1.y; a1.z += c * c1.z; a1.w += c * c1.w;
        }
    }

    // overflow list (cold path; one uniform load when empty)
    int oc = *ovf_cnt; if (oc > OVFCAP) oc = OVFCAP;
    for (int i = 0; i < oc; i++) {
        int key = ovf_key[i];
        if ((key >> 11) == row) {
            float c = ovf_c[i];
            int tg = ((row >> 11) << 11) | (key & 2047);   // b*T + tloc
            const float4* xp4 = (const float4*)(x + (size_t)tg * D);
            float4 v0 = xp4[lane], v1 = xp4[lane + 64];
            a0.x += c * v0.x; a0.y += c * v0.y; a0.z += c * v0.z; a0.w += c * v0.w;
            a1.x += c * v1.x; a1.y += c * v1.y; a1.z += c * v1.z; a1.w += c * v1.w;
        }
    }

    float ss = a0.x * a0.x + a0.y * a0.y + a0.z * a0.z + a0.w * a0.w
             + a1.x * a1.x + a1.y * a1.y + a1.z * a1.z + a1.w * a1.w;
#pragma unroll
    for (int off = 32; off > 0; off >>= 1) ss += __shfl_xor(ss, off, 64);
    float sc = 1.0f / (sqrtf(ss) + 1e-6f);
    a0.x *= sc; a0.y *= sc; a0.z *= sc; a0.w *= sc;
    a1.x *= sc; a1.y *= sc; a1.z *= sc; a1.w *= sc;
    float4* vp4 = (float4*)(val1 + (size_t)row * D);
    vp4[lane] = a0; vp4[lane + 64] = a1;

    // ---- stage rows to LDS, then q/kT projection (k_qk structure, NR=4) ----
    {
        float4* vr = (float4*)&vrow[wv][0];
        vr[lane] = a0; vr[lane + 64] = a1;
    }
    __syncthreads();

    int r = lane, grp = wv;
    float accq[4], acck[4];
#pragma unroll
    for (int rr = 0; rr < 4; rr++) { accq[rr] = 0.f; acck[rr] = 0.f; }
    for (int d0 = grp * 128; d0 < grp * 128 + 128; d0 += 4) {
#pragma unroll
        for (int dd = 0; dd < 4; dd++) {
            float a  = pair_a[(size_t)(d0 + dd) * R + r];
            float bb = pair_b[(size_t)(d0 + dd) * R + r];
#pragma unroll
            for (int rr = 0; rr < 4; rr++) {
                float v = vrow[rr][d0 + dd];
                accq[rr] += v * a;
                acck[rr] += v * bb;
            }
        }
    }
#pragma unroll
    for (int rr = 0; rr < 4; rr++) {
        redq[rr][tid] = accq[rr];
        redk[rr][tid] = acck[rr];
    }
    __syncthreads();
    {
        int rr = tid >> 6, r2 = tid & 63;
        float qv = redq[rr][r2] + redq[rr][64 + r2] +
                   redq[rr][128 + r2] + redq[rr][192 + r2];
        float kv = redk[rr][r2] + redk[rr][64 + r2] +
                   redk[rr][128 + r2] + redk[rr][192 + r2];
        q[(size_t)(rowbase + rr) * R + r2] = qv;
        kkT[((size_t)b * R + r2) * S + (sbase + rr)] = kv;
    }
}

// ---------- state reduce: base softmax + per-b (m, 1/sum) of base+delta ------
// One block, 512 threads.
__global__ void __launch_bounds__(512) k_state_red(const float* __restrict__ init_state,
                                                   const float* __restrict__ state_ws,
                                                   float* base_ws,
                                                   float* sm_m, float* sm_inv) {
    __shared__ float red[16];
    __shared__ float base_lds[S];   // 8 KB
    int tid = threadIdx.x, lane = tid & 63, wv = tid >> 6;

    // Phase A: base = sign * softmax(|init_state|)  (2048 values, 4 per thread)
    float4 v = ((const float4*)init_state)[tid];
    float m = fmaxf(fmaxf(fabsf(v.x), fabsf(v.y)), fmaxf(fabsf(v.z), fabsf(v.w)));
#pragma unroll
    for (int off = 32; off > 0; off >>= 1) m = fmaxf(m, __shfl_xor(m, off, 64));
    if (lane == 0) red[wv] = m;
    __syncthreads();
    float M = red[0];
#pragma unroll
    for (int i = 1; i < 8; i++) M = fmaxf(M, red[i]);
    __syncthreads();
    float s = expf(fabsf(v.x) - M) + expf(fabsf(v.y) - M) +
              expf(fabsf(v.z) - M) + expf(fabsf(v.w) - M);
#pragma unroll
    for (int off = 32; off > 0; off >>= 1) s += __shfl_xor(s, off, 64);
    if (lane == 0) red[wv] = s;
    __syncthreads();
    float SUM = 0.f;
#pragma unroll
    for (int i = 0; i < 8; i++) SUM += red[i];
    float inv = 1.0f / SUM;
    float4 bo;
    bo.x = signf(v.x) * expf(fabsf(v.x) - M) * inv;
    bo.y = signf(v.y) * expf(fabsf(v.y) - M) * inv;
    bo.z = signf(v.z) * expf(fabsf(v.z) - M) * inv;
    bo.w = signf(v.w) * expf(fabsf(v.w) - M) * inv;
    ((float4*)base_ws)[tid] = bo;
    ((float4*)base_lds)[tid] = bo;
    __syncthreads();

    // Phase B: wave wv = b; combined = base + delta; per-b max & expsum
    int b = wv;
    const float4* dp = (const float4*)(state_ws + (size_t)b * S);
    const float4* bp = (const float4*)base_lds;
    float4 c[8];
    float vm = 0.f;
#pragma unroll
    for (int i = 0; i < 8; i++) {
        float4 dv = dp[lane + 64 * i];
        float4 bv = bp[lane + 64 * i];
        c[i].x = bv.x + dv.x; c[i].y = bv.y + dv.y;
        c[i].z = bv.z + dv.z; c[i].w = bv.w + dv.w;
        vm = fmaxf(vm, fmaxf(fmaxf(fabsf(c[i].x), fabsf(c[i].y)),
                             fmaxf(fabsf(c[i].z), fabsf(c[i].w))));
    }
#pragma unroll
    for (int off = 32; off > 0; off >>= 1) vm = fmaxf(vm, __shfl_xor(vm, off, 64));
    float sum = 0.f;
#pragma unroll
    for (int i = 0; i < 8; i++) {
        sum += expf(fabsf(c[i].x) - vm) + expf(fabsf(c[i].y) - vm) +
               expf(fabsf(c[i].z) - vm) + expf(fabsf(c[i].w) - vm);
    }
#pragma unroll
    for (int off = 32; off > 0; off >>= 1) sum += __shfl_xor(sum, off, 64);
    if (lane == 0) { sm_m[b] = vm; sm_inv[b] = 1.0f / sum; }
}

// ---------- pscore+mix: p = q.kT, topk, gather neighbors, write out ----------
// Fusion of the former k_pscore and k_mix; eidx/ew stay in registers.
__global__ void __launch_bounds__(512) k_pscore_mix(const float* __restrict__ q,
                                                    const float* __restrict__ kkT,
                                                    const float* __restrict__ val1,
                                                    const float* __restrict__ base_ws,
                                                    const float* __restrict__ state_ws,
                                                    const float* __restrict__ sm_m,
                                                    const float* __restrict__ sm_inv,
                                                    float* __restrict__ out) {
    __shared__ __align__(16) float prow[NI][S];   // 64 KB
    __shared__ __align__(16) float qrow[NI][R];   // 2 KB
    __shared__ unsigned long long cand[NI][64];   // 4 KB

    int tid = threadIdx.x;
    int lane = tid & 63, wv = tid >> 6;
    int blk = ((blockIdx.x & 7) << 8) | (blockIdx.x >> 3);  // XCD k <-> b=k
    int ibase = blk * NI;            // global row base (never straddles b)
    int b = ibase >> 11;             // S = 2048

    {
        int rr = tid >> 6, r = tid & 63;
        qrow[rr][r] = q[(size_t)(ibase + rr) * R + r];
    }
    __syncthreads();

    // p rows (float4 over j; kkT slice reused by 8 rows)
    {
        const float4* kk4 = (const float4*)(kkT + (size_t)b * R * S);
        int j4 = tid;                // 512 threads cover S/4 = 512
        float4 acc[NI];
#pragma unroll
        for (int rr = 0; rr < NI; rr++) acc[rr] = make_float4(0.f, 0.f, 0.f, 0.f);
        for (int r0 = 0; r0 < R; r0 += 4) {
            float4 qv[NI];
#pragma unroll
            for (int rr = 0; rr < NI; rr++) qv[rr] = *(const float4*)&qrow[rr][r0];
#define P_STEP(dr, comp)                                                       \
            {                                                                  \
                float4 kv = kk4[(size_t)(r0 + dr) * (S / 4) + j4];             \
                _Pragma("unroll")                                              \
                for (int rr = 0; rr < NI; rr++) {                              \
                    float c = qv[rr].comp;                                     \
                    acc[rr].x += c * kv.x; acc[rr].y += c * kv.y;              \
                    acc[rr].z += c * kv.z; acc[rr].w += c * kv.w;              \
                }                                                              \
            }
            P_STEP(0, x) P_STEP(1, y) P_STEP(2, z) P_STEP(3, w)
#undef P_STEP
        }
#pragma unroll
        for (int rr = 0; rr < NI; rr++)
            ((float4*)&prow[rr][0])[j4] = acc[rr];
    }
    __syncthreads();

    // ---- per-wave topk on row ibase + wv (8 waves, 8 rows) ----
    int row = ibase + wv;
    float myg; int myj;
    topk16_row(&prow[wv][0], &cand[wv][0], lane, myg, myj);

    float m = __shfl(fabsf(myg), 0);
    float e = (lane < KTOP) ? expf(fabsf(myg) - m) : 0.f;
    float esum = e;
#pragma unroll
    for (int off = 8; off > 0; off >>= 1) esum += __shfl_xor(esum, off, 64);
    esum = __shfl(esum, 0);
    float myw = signf(myg) * e / esum;

    // ---- mix: gather neighbors, residual add, unit-norm, full out row ----
    const float4* self4 = (const float4*)(val1 + (size_t)row * D);
    float4 a0 = self4[lane], a1 = self4[lane + 64];
#pragma unroll
    for (int k = 0; k < KTOP; k++) {
        int j = __shfl(myj, k);
        float w = __shfl(myw, k);
        const float4* nb4 = (const float4*)(val1 + ((size_t)b * S + j) * D);
        float4 v0 = nb4[lane], v1 = nb4[lane + 64];
        a0.x += w * v0.x; a0.y += w * v0.y; a0.z += w * v0.z; a0.w += w * v0.w;
        a1.x += w * v1.x; a1.y += w * v1.y; a1.z += w * v1.z; a1.w += w * v1.w;
    }
    float ss = a0.x * a0.x + a0.y * a0.y + a0.z * a0.z + a0.w * a0.w
             + a1.x * a1.x + a1.y * a1.y + a1.z * a1.z + a1.w * a1.w;
#pragma unroll
    for (int off = 32; off > 0; off >>= 1) ss += __shfl_xor(ss, off, 64);
    float scale = 1.0f / (sqrtf(ss) + 1e-6f);
    float* op = out + (size_t)row * (D + 1) + 1;
    int d0 = 4 * lane;
    op[d0 + 0] = a0.x * scale; op[d0 + 1] = a0.y * scale;
    op[d0 + 2] = a0.z * scale; op[d0 + 3] = a0.w * scale;
    op[256 + d0 + 0] = a1.x * scale; op[256 + d0 + 1] = a1.y * scale;
    op[256 + d0 + 2] = a1.z * scale; op[256 + d0 + 3] = a1.w * scale;

    // state output column
    if (lane == 0) {
        float vv = base_ws[row & (S - 1)] + state_ws[row];
        out[(size_t)row * (D + 1)] =
            signf(vv) * expf(fabsf(vv) - sm_m[b]) * sm_inv[b];
    }
}

extern "C" void kernel_launch(void* const* d_in, const int* in_sizes, int n_in,
                              void* d_out, int out_size, void* d_ws, size_t ws_size,
                              hipStream_t stream) {
    (void)in_sizes; (void)n_in; (void)out_size; (void)ws_size;
    const float* x          = (const float*)d_in[0];
    const float* init_state = (const float*)d_in[1];
    const float* init_val   = (const float*)d_in[2];
    const float* route_a    = (const float*)d_in[3];
    const float* route_b    = (const float*)d_in[4];
    const float* pair_a     = (const float*)d_in[5];
    const float* pair_b     = (const float*)d_in[6];
    float* out = (float*)d_out;

    float* ws       = (float*)d_ws;
    float* val1     = ws;                             // B*S*D
    float* q        = val1 + (size_t)B * S * D;       // B*S*R
    float* kkT      = q    + (size_t)B * S * R;       // B*R*S
    float* coef     = kkT  + (size_t)B * R * S;       // B*T*K
    int*   binlist  = (int*)(coef + (size_t)B * T * KTOP);   // B*S*CAP
    // --- zero region (one memset): state deltas + bincount + ovf_cnt ---
    float* state_ws = (float*)(binlist + (size_t)B * S * CAP);  // B*S
    int*   bincount = (int*)(state_ws + (size_t)B * S);         // B*S
    int*   ovf_cnt  = bincount + (size_t)B * S;                 // 16 (pad)
    // --- end zero region ---
    int*   ovf_key  = ovf_cnt + 16;                             // OVFCAP
    float* ovf_c    = (float*)(ovf_key + OVFCAP);               // OVFCAP
    float* base_ws  = ovf_c + OVFCAP;                           // S
    float* sm_m     = base_ws + S;                              // B
    float* sm_inv   = sm_m + B;                                 // B

    hipMemsetAsync(state_ws, 0, (size_t)(2 * B * S + 16) * sizeof(int), stream);
    hipLaunchKernelGGL(k_score, dim3(B * T / NT), dim3(512), 0, stream,
                       x, route_a, route_b, state_ws, coef, bincount, binlist,
                       ovf_cnt, ovf_key, ovf_c);
    hipLaunchKernelGGL(k_state_red, dim3(1), dim3(512), 0, stream,
                       init_state, state_ws, base_ws, sm_m, sm_inv);
    hipLaunchKernelGGL(k_accum_qk, dim3(B * S / 4), dim3(256), 0, stream,
                       x, init_val, coef, bincount, binlist,
                       ovf_cnt, ovf_key, ovf_c, pair_a, pair_b, val1, q, kkT);
    hipLaunchKernelGGL(k_pscore_mix, dim3(B * S / NI), dim3(512), 0, stream,
                       q, kkT, val1, base_ws, state_ws, sm_m, sm_inv, out);
}